// Round 4
// baseline (2329.613 us; speedup 1.0000x reference)
//
#include <hip/hip_runtime.h>
#include <math.h>

#define HID  128
#define EDIM 4

typedef unsigned short u16;
typedef u16    us8   __attribute__((ext_vector_type(8)));
typedef __bf16 bf16x8 __attribute__((ext_vector_type(8)));
typedef float  f32x4 __attribute__((ext_vector_type(4)));

// silu via hw rcp: v_rcp_f32 (~1 ulp) instead of IEEE div (10+ inst w/o fast-math)
__device__ __forceinline__ float silu_f(float v) {
    return v * __builtin_amdgcn_rcpf(1.0f + __expf(-v));
}
__device__ __forceinline__ u16 f2bf(float f) {   // RNE fp32->bf16 (cold paths)
    unsigned u = __float_as_uint(f);
    unsigned r = u + 0x7fffu + ((u >> 16) & 1u);
    return (u16)(r >> 16);
}
__device__ __forceinline__ u16 f2bf_fast(float f) {  // round-half-up, 2 ops (hot)
    return (u16)((__float_as_uint(f) + 0x8000u) >> 16);
}
// pack two fp32 -> one u32 of 2 bf16 (round-half-up)
__device__ __forceinline__ unsigned pack_bf2(float a, float b) {
    return ((__float_as_uint(a) + 0x8000u) >> 16) |
           ((__float_as_uint(b) + 0x8000u) & 0xffff0000u);
}
__device__ __forceinline__ float bf2f(u16 s) {
    return __uint_as_float(((unsigned)s) << 16);
}
__device__ __forceinline__ bf16x8 as_bf(us8 v) {
    return __builtin_bit_cast(bf16x8, v);
}

// ---------------- fused setup: weight swizzle + zero-fills ------------------
// Generalized fragment swizzler: logical k -> source row = k + (k>=split ?
// jump : 0); valid iff row < Kdata. Layer stride Kstride rows.
__device__ __forceinline__ void wfrag_gen(const float* __restrict__ w,
        u16* __restrict__ out, int KT, int Kdata, int Kstride,
        int split, int jump, int idx) {
    int lane = idx & 63;
    int f    = (idx >> 6) % (KT * 8);
    int l    = idx / (64 * KT * 8);
    int kt = f >> 3, nt = f & 7;
    int n  = nt * 16 + (lane & 15);
    int k0 = kt * 32 + ((lane >> 4) * 8);
    us8 v;
    #pragma unroll
    for (int j = 0; j < 8; ++j) {
        int k = k0 + j;
        int row = k + (k >= split ? jump : 0);
        v[j] = (row < Kdata) ? f2bf(w[((size_t)l * Kstride + row) * HID + n]) : (u16)0;
    }
    *(us8*)&out[((size_t)(l * KT * 8 + f) * 64 + lane) * 8] = v;
}

// W1 [260x128] split: w1a (src rows 0..127 + attr rows 256..259 -> KT=5),
// w1b (dst rows 128..255 -> KT=4; consumed by y_kernel / fused Y-GEMM).
#define T1A (4 * 5 * 8 * 64)
#define T1B (4 * 4 * 8 * 64)
#define T2  (4 * 4 * 8 * 64)
#define T3  (4 * 8 * 8 * 64)

__global__ __launch_bounds__(256) void setup_kernel(
        const float* __restrict__ ew1, const float* __restrict__ ew2,
        const float* __restrict__ nw,
        u16* __restrict__ w1af, u16* __restrict__ w1bf,
        u16* __restrict__ w2f, u16* __restrict__ nwf,
        int* __restrict__ cnt, int* __restrict__ cursor,
        float* __restrict__ sums, float* __restrict__ cnts_g, int N, int G) {
    const int BIG = 1 << 30;
    int idx = blockIdx.x * 256 + threadIdx.x;
    if (idx < T1A) { wfrag_gen(ew1, w1af, 5, 260, 260, 128, 128, idx); return; }
    idx -= T1A;
    if (idx < T1B) { wfrag_gen(ew1, w1bf, 4, 260, 260, 0, 128, idx); return; }
    idx -= T1B;
    if (idx < T2) { wfrag_gen(ew2, w2f, 4, 128, 128, BIG, 0, idx); return; }
    idx -= T2;
    if (idx < T3) { wfrag_gen(nw, nwf, 8, 256, 256, BIG, 0, idx); return; }
    idx -= T3;
    if (idx < N) { cnt[idx] = 0; return; }
    idx -= N;
    if (idx < N) { cursor[idx] = 0; return; }
    idx -= N;
    if (idx < G * HID) { sums[idx] = 0.f; return; }
    idx -= G * HID;
    if (idx < G) { cnts_g[idx] = 0.f; return; }
}

// ---------------- CSR build: hist -> scan -> scatter ------------------------
__global__ __launch_bounds__(256) void hist_kernel(const int* __restrict__ dst,
        int* __restrict__ cnt, int E) {
    int e = blockIdx.x * 256 + threadIdx.x;
    if (e < E) atomicAdd(&cnt[dst[e]], 1);
}

__global__ __launch_bounds__(1024) void scan_kernel(const int* __restrict__ cnt,
        int* __restrict__ rowptr, int n) {
    __shared__ int s[1024];
    const int t = threadIdx.x;
    const int chunk = (n + 1023) >> 10;
    int lo = t * chunk, hi = lo + chunk;
    if (lo > n) lo = n;
    if (hi > n) hi = n;
    int sum = 0;
    for (int i = lo; i < hi; ++i) sum += cnt[i];
    s[t] = sum;
    __syncthreads();
    for (int off = 1; off < 1024; off <<= 1) {
        int v = (t >= off) ? s[t - off] : 0;
        __syncthreads();
        s[t] += v;
        __syncthreads();
    }
    int run = s[t] - sum;
    for (int i = lo; i < hi; ++i) { rowptr[i] = run; run += cnt[i]; }
    if (t == 1023) rowptr[n] = run;
}

__global__ __launch_bounds__(256) void scatter_kernel(const int* __restrict__ src,
        const int* __restrict__ dst, const float* __restrict__ ea,
        const int* __restrict__ rowptr, int* __restrict__ cursor,
        int* __restrict__ srcS, int* __restrict__ dstS, u16* __restrict__ eaS, int E) {
    int e = blockIdx.x * 256 + threadIdx.x;
    if (e >= E) return;
    int d = dst[e];
    int p = rowptr[d] + atomicAdd(&cursor[d], 1);
    srcS[p] = src[e];
    dstS[p] = d;
    const float* q = &ea[(size_t)e * EDIM];
    ushort4 v;
    v.x = f2bf(q[0]); v.y = f2bf(q[1]); v.z = f2bf(q[2]); v.w = f2bf(q[3]);
    *(ushort4*)&eaS[(size_t)p * 4] = v;
}

// embed + graph counts (fused); no global agg anymore (agg lives in LDS)
__global__ __launch_bounds__(HID) void embed_kernel(const int* __restrict__ z,
        const float* __restrict__ emb, u16* __restrict__ xb,
        const int* __restrict__ batch, float* __restrict__ counts, int n) {
    int i = blockIdx.x;
    if (i >= n) return;
    int t = threadIdx.x;
    xb[(size_t)i * HID + t] = f2bf(emb[(size_t)z[i] * HID + t]);
    if (t == 0) unsafeAtomicAdd(&counts[batch[i]], 1.0f);
}

// ---------------- per-node dst-projection: Y = x @ W1b (fp32 out) -----------
// Only used for layer 0; layers 1-3 get Y fused from fused_layer's Y-GEMM.
__global__ __launch_bounds__(256) void y_kernel(
        const u16* __restrict__ xb, const u16* __restrict__ w1bf,
        float* __restrict__ Y, int n) {
    const int t    = threadIdx.x;
    const int i0   = blockIdx.x * 32;
    const int wv   = t >> 6, lane = t & 63;
    const int lrow = lane & 15;
    const int kq   = lane >> 4;
    const int kq8  = kq * 8;

    int iN[2];
    #pragma unroll
    for (int mt = 0; mt < 2; ++mt) {
        int i = i0 + mt * 16 + lrow; if (i >= n) i = n - 1;
        iN[mt] = i;
    }
    f32x4 acc[2][2];
    #pragma unroll
    for (int mt = 0; mt < 2; ++mt)
        #pragma unroll
        for (int nt = 0; nt < 2; ++nt)
            acc[mt][nt] = (f32x4){0.f, 0.f, 0.f, 0.f};

    #pragma unroll
    for (int kt = 0; kt < 4; ++kt) {
        bf16x8 w0 = *(const bf16x8*)&w1bf[((size_t)(kt * 8 + wv * 2 + 0) * 64 + lane) * 8];
        bf16x8 w1 = *(const bf16x8*)&w1bf[((size_t)(kt * 8 + wv * 2 + 1) * 64 + lane) * 8];
        #pragma unroll
        for (int mt = 0; mt < 2; ++mt) {
            bf16x8 a = as_bf(*(const us8*)&xb[(size_t)iN[mt] * HID + kt * 32 + kq8]);
            acc[mt][0] = __builtin_amdgcn_mfma_f32_16x16x32_bf16(w0, a, acc[mt][0], 0, 0, 0);
            acc[mt][1] = __builtin_amdgcn_mfma_f32_16x16x32_bf16(w1, a, acc[mt][1], 0, 0, 0);
        }
    }
    #pragma unroll
    for (int mt = 0; mt < 2; ++mt) {
        int node = i0 + mt * 16 + lrow;
        if (node < n) {
            #pragma unroll
            for (int nt = 0; nt < 2; ++nt)
                *(f32x4*)&Y[(size_t)node * HID + (wv * 2 + nt) * 16 + kq * 4] = acc[mt][nt];
        }
    }
}

// ---------------- fused layer: edge MLP + scatter + node MLP + next-Y -------
// R19: block owns 32 consecutive NODES and (via CSR) exactly their incoming
// edges [rowptr[n0], rowptr[n0+32]) — avg 512 edges = 8 x 64-edge tiles,
// sd ~23 (random graph -> balanced). agg accumulates in LDS (atomicAdd on
// aggL; global agg array + its atomics + re-read + re-zero ELIMINATED).
// Node GEMM + next layer's Y-GEMM fused at the tail. x ping-pong (xin/xout)
// removes the cross-block read-write race. Y update is in-place safe: each
// block touches only its own nodes' Y rows, barrier-ordered.
// Edge-phase math copied verbatim from R17 (bit-identical).
// FAILED variants (do not reintroduce): R9 XOR-swizzle 32KB (235 us),
// R13 2x2 wave tiling (164 us), R16 occupancy 2x (flat; throughput-bound),
// R18 VGPR-persistent weights (compiler caps at 64 VGPR -> scratch spill,
// WRITE_SIZE +71MB, 197 us).
__global__ __launch_bounds__(512, 6) void fused_layer(
        const u16* __restrict__ xin, u16* __restrict__ xout,
        const int* __restrict__ srcS, const int* __restrict__ dstS,
        const u16* __restrict__ eaS, const int* __restrict__ rowptr,
        const u16* __restrict__ w1af, const float* __restrict__ b1,
        const u16* __restrict__ w2f, const float* __restrict__ b2,
        float* __restrict__ Y, const u16* __restrict__ w1bf_nxt,
        const u16* __restrict__ nwf, const float* __restrict__ nb,
        const int* __restrict__ batch, float* __restrict__ sums,
        int last, int N) {
    // A: u16 [64][168] (dead after GEMM1) | H: u16 [64][136] | M: f32 [64][132]
    // xnS: u16 [32][128] (aliases A after edge phase)
    __shared__ __align__(16) char smem[64 * 132 * 4];
    __shared__ __align__(16) int dsh[64];
    __shared__ __align__(16) float aggL[32 * HID];
    u16*   A   = (u16*)smem;
    u16*   H   = (u16*)smem;
    float* M   = (float*)smem;
    u16*   xnS = (u16*)smem;

    const int t    = threadIdx.x;
    const int wv   = t >> 6, lane = t & 63;
    const int lrow = lane & 15;
    const int kq   = lane >> 4;
    const int kq8  = kq * 8;
    const int rq   = kq * 4;
    const int h    = wv >> 2;     // edge-half this wave owns (0/1)
    const int p    = wv & 3;      // col-pair this wave owns (0..3)

    const int n0  = blockIdx.x * 32;
    int nhi = n0 + 32; if (nhi > N) nhi = N;
    const int rs = rowptr[n0];
    const int re = rowptr[nhi];
    const int ntiles = (re - rs + 63) >> 6;

    // zero LDS agg (first loop-top barrier orders this before any scan-add)
    #pragma unroll
    for (int i = 0; i < 2; ++i)
        ((f32x4*)aggL)[i * 512 + t] = (f32x4){0.f, 0.f, 0.f, 0.f};

    for (int tile = 0; tile < ntiles; ++tile) {
        const int e0 = rs + tile * 64;
        __syncthreads();   // prior tile's scan reads of M (aliases A) complete

        // ---- stage A: 64 rows x 16 src-chunks of 8 bf16 ----
        #pragma unroll
        for (int it = 0; it < 2; ++it) {
            int slot = it * 512 + t;           // 1024 slots
            int row = slot >> 4, ch = slot & 15;
            int e = e0 + row; if (e >= re) e = re - 1;
            int node = srcS[e];
            us8 v = *(const us8*)&xin[(size_t)node * HID + ch * 8];
            *(us8*)&A[row * 168 + ch * 8] = v;
        }
        if (t < 64) {
            int e = e0 + t;
            bool valid = e < re; if (!valid) e = re - 1;
            dsh[t] = valid ? (dstS[e] - n0) : -1;   // LOCAL node idx 0..31
            ushort4 q = *(const ushort4*)&eaS[(size_t)e * 4];
            int base = t * 168 + 128;
            us8 z8 = (us8){0, 0, 0, 0, 0, 0, 0, 0};
            *(us8*)&A[base + 8]  = z8;         // cols 136..159 zero (K-pad)
            *(us8*)&A[base + 16] = z8;
            *(us8*)&A[base + 24] = z8;
            A[base + 0] = q.x; A[base + 1] = q.y; A[base + 2] = q.z; A[base + 3] = q.w;
            A[base + 4] = 0;   A[base + 5] = 0;   A[base + 6] = 0;   A[base + 7] = 0;
        }
        __syncthreads();

        // ---- GEMM1: K=160 (src+attr). acc init = b1 + Y[n0+dsh] (dedup'd dst).
        f32x4 acc[2][2];
        #pragma unroll
        for (int mt = 0; mt < 2; ++mt) {
            int edge = (h * 2 + mt) * 16 + lrow;
            int d = dsh[edge]; if (d < 0) d = 0;   // tail-safe (unused result)
            #pragma unroll
            for (int nt = 0; nt < 2; ++nt) {
                f32x4 bv = *(const f32x4*)&b1[(p * 2 + nt) * 16 + rq];
                f32x4 yv = *(const f32x4*)&Y[(size_t)(n0 + d) * HID + (p * 2 + nt) * 16 + rq];
                acc[mt][nt] = bv + yv;
            }
        }
        #pragma unroll
        for (int kt = 0; kt < 5; ++kt) {
            bf16x8 w0 = *(const bf16x8*)&w1af[((size_t)(kt * 8 + p * 2 + 0) * 64 + lane) * 8];
            bf16x8 w1 = *(const bf16x8*)&w1af[((size_t)(kt * 8 + p * 2 + 1) * 64 + lane) * 8];
            #pragma unroll
            for (int mt = 0; mt < 2; ++mt) {
                bf16x8 a = *(const bf16x8*)&A[((h * 2 + mt) * 16 + lrow) * 168 + kt * 32 + kq8];
                acc[mt][0] = __builtin_amdgcn_mfma_f32_16x16x32_bf16(w0, a, acc[mt][0], 0, 0, 0);
                acc[mt][1] = __builtin_amdgcn_mfma_f32_16x16x32_bf16(w1, a, acc[mt][1], 0, 0, 0);
            }
        }
        __syncthreads();   // all A reads done; region reused as H

        // silu -> H: 4 consecutive n per lane -> one packed b64 per (mt,nt)
        #pragma unroll
        for (int mt = 0; mt < 2; ++mt)
            #pragma unroll
            for (int nt = 0; nt < 2; ++nt) {
                uint2 hv;
                hv.x = pack_bf2(silu_f(acc[mt][nt][0]), silu_f(acc[mt][nt][1]));
                hv.y = pack_bf2(silu_f(acc[mt][nt][2]), silu_f(acc[mt][nt][3]));
                int edge = (h * 2 + mt) * 16 + lrow;
                *(uint2*)&H[edge * 136 + (p * 2 + nt) * 16 + rq] = hv;
            }
        __syncthreads();

        // ---- GEMM2: [64 x 128] @ [128 x 128], swapped operands ----
        f32x4 acc2[2][2];
        #pragma unroll
        for (int nt = 0; nt < 2; ++nt) {
            f32x4 bv = *(const f32x4*)&b2[(p * 2 + nt) * 16 + rq];
            acc2[0][nt] = bv; acc2[1][nt] = bv;
        }
        #pragma unroll
        for (int kt = 0; kt < 4; ++kt) {
            bf16x8 w0 = *(const bf16x8*)&w2f[((size_t)(kt * 8 + p * 2 + 0) * 64 + lane) * 8];
            bf16x8 w1 = *(const bf16x8*)&w2f[((size_t)(kt * 8 + p * 2 + 1) * 64 + lane) * 8];
            #pragma unroll
            for (int mt = 0; mt < 2; ++mt) {
                bf16x8 a = *(const bf16x8*)&H[((h * 2 + mt) * 16 + lrow) * 136 + kt * 32 + kq8];
                acc2[mt][0] = __builtin_amdgcn_mfma_f32_16x16x32_bf16(w0, a, acc2[mt][0], 0, 0, 0);
                acc2[mt][1] = __builtin_amdgcn_mfma_f32_16x16x32_bf16(w1, a, acc2[mt][1], 0, 0, 0);
            }
        }
        __syncthreads();   // all H reads complete before M overwrites (aliased WAR)

        // silu -> M: fp32 messages, one float4 store per (mt,nt)
        #pragma unroll
        for (int mt = 0; mt < 2; ++mt)
            #pragma unroll
            for (int nt = 0; nt < 2; ++nt) {
                f32x4 mv;
                #pragma unroll
                for (int r = 0; r < 4; ++r) mv[r] = silu_f(acc2[mt][nt][r]);
                int edge = (h * 2 + mt) * 16 + lrow;
                *(f32x4*)&M[edge * 132 + (p * 2 + nt) * 16 + rq] = mv;
            }

        // ---- wave-local segmented reduction into LDS agg (local node idx).
        // Wave (h,p) scans exactly the 32x32 M region it wrote (no barrier;
        // intra-wave DS program order). LDS atomicAdd handles the rare
        // boundary-node collision between the two 16-row lane halves.
        {
            int col = p * 32 + (lane & 31);
            int r0  = h * 32 + (lane >> 5) * 16;   // rows r0..r0+15
            int4 da = *(const int4*)&dsh[r0];
            int4 db = *(const int4*)&dsh[r0 + 4];
            int4 dc = *(const int4*)&dsh[r0 + 8];
            int4 dd = *(const int4*)&dsh[r0 + 12];
            int ds_[16] = {da.x, da.y, da.z, da.w, db.x, db.y, db.z, db.w,
                           dc.x, dc.y, dc.z, dc.w, dd.x, dd.y, dd.z, dd.w};
            float run = 0.f;
            int   cur = ds_[0];
            #pragma unroll
            for (int i = 0; i < 16; ++i) {
                run += M[(r0 + i) * 132 + col];
                int nxt = (i == 15) ? -2 : ds_[i + 1];
                if (cur != nxt) {             // uniform within 32-lane half
                    if (cur >= 0)
                        atomicAdd(&aggL[cur * HID + col], run);
                    run = 0.f; cur = nxt;
                }
            }
        }
    }
    __syncthreads();   // all edge tiles done; aggL complete; A region free

    // ---- node GEMM: x_new = silu([x | aggL] @ nw + nb), 8 waves x 16 cols --
    // wave wv owns n-tile wv (cols wv*16..+15); lane holds node = mt*16+lrow,
    // cols wv*16 + rq + r  (swapped-operand layout, same as edge GEMMs).
    f32x4 accN[2];
    #pragma unroll
    for (int mt = 0; mt < 2; ++mt)
        accN[mt] = *(const f32x4*)&nb[wv * 16 + rq];
    #pragma unroll
    for (int kt = 0; kt < 4; ++kt) {     // x part (k 0..127), global reads
        bf16x8 w = *(const bf16x8*)&nwf[((size_t)(kt * 8 + wv) * 64 + lane) * 8];
        #pragma unroll
        for (int mt = 0; mt < 2; ++mt) {
            int nd = n0 + mt * 16 + lrow; if (nd >= N) nd = N - 1;
            bf16x8 a = as_bf(*(const us8*)&xin[(size_t)nd * HID + kt * 32 + kq8]);
            accN[mt] = __builtin_amdgcn_mfma_f32_16x16x32_bf16(w, a, accN[mt], 0, 0, 0);
        }
    }
    #pragma unroll
    for (int kt = 4; kt < 8; ++kt) {     // agg part (k 128..255), LDS fp32 -> bf16
        bf16x8 w = *(const bf16x8*)&nwf[((size_t)(kt * 8 + wv) * 64 + lane) * 8];
        #pragma unroll
        for (int mt = 0; mt < 2; ++mt) {
            const float* pa = &aggL[(mt * 16 + lrow) * HID + (kt - 4) * 32 + kq8];
            f32x4 f0 = *(const f32x4*)pa;
            f32x4 f1 = *(const f32x4*)(pa + 4);
            us8 av;
            av[0] = f2bf_fast(f0[0]); av[1] = f2bf_fast(f0[1]);
            av[2] = f2bf_fast(f0[2]); av[3] = f2bf_fast(f0[3]);
            av[4] = f2bf_fast(f1[0]); av[5] = f2bf_fast(f1[1]);
            av[6] = f2bf_fast(f1[2]); av[7] = f2bf_fast(f1[3]);
            accN[mt] = __builtin_amdgcn_mfma_f32_16x16x32_bf16(w, as_bf(av), accN[mt], 0, 0, 0);
        }
    }

    if (!last) {
        // x_new -> global xout (ping-pong) + LDS xnS for the fused Y-GEMM
        #pragma unroll
        for (int mt = 0; mt < 2; ++mt) {
            uint2 xv;
            xv.x = pack_bf2(silu_f(accN[mt][0]), silu_f(accN[mt][1]));
            xv.y = pack_bf2(silu_f(accN[mt][2]), silu_f(accN[mt][3]));
            int node = mt * 16 + lrow;
            *(uint2*)&xnS[node * HID + wv * 16 + rq] = xv;
            if (n0 + node < N)
                *(uint2*)&xout[(size_t)(n0 + node) * HID + wv * 16 + rq] = xv;
        }
        __syncthreads();   // xnS complete before cross-wave reads

        // ---- Y-GEMM for NEXT layer: Y = x_new @ W1b_next (in-place rows) ----
        f32x4 accY[2];
        accY[0] = (f32x4){0.f, 0.f, 0.f, 0.f};
        accY[1] = (f32x4){0.f, 0.f, 0.f, 0.f};
        #pragma unroll
        for (int kt = 0; kt < 4; ++kt) {
            bf16x8 w = *(const bf16x8*)&w1bf_nxt[((size_t)(kt * 8 + wv) * 64 + lane) * 8];
            #pragma unroll
            for (int mt = 0; mt < 2; ++mt) {
                bf16x8 a = as_bf(*(const us8*)&xnS[(mt * 16 + lrow) * HID + kt * 32 + kq8]);
                accY[mt] = __builtin_amdgcn_mfma_f32_16x16x32_bf16(w, a, accY[mt], 0, 0, 0);
            }
        }
        #pragma unroll
        for (int mt = 0; mt < 2; ++mt) {
            int node = mt * 16 + lrow;
            if (n0 + node < N)
                *(f32x4*)&Y[(size_t)(n0 + node) * HID + wv * 16 + rq] = accY[mt];
        }
    } else {
        // final layer: scatter silu straight into per-graph sums
        #pragma unroll
        for (int mt = 0; mt < 2; ++mt) {
            int node = mt * 16 + lrow;
            if (n0 + node < N) {
                int b = batch[n0 + node];
                #pragma unroll
                for (int r = 0; r < 4; ++r)
                    unsafeAtomicAdd(&sums[(size_t)b * HID + wv * 16 + rq + r],
                                    silu_f(accN[mt][r]));
            }
        }
    }
}

// ---------------- readout ---------------------------------------------------
__global__ __launch_bounds__(HID) void readout_kernel(
        const float* __restrict__ sums, const float* __restrict__ counts,
        const float* __restrict__ rw1, const float* __restrict__ rb1,
        const float* __restrict__ rw2, const float* __restrict__ rb2,
        float* __restrict__ pred) {
    __shared__ float gv[HID];
    __shared__ float hv[HID];
    const int g = blockIdx.x;
    const int t = threadIdx.x;
    float c = counts[g];
    if (c < 1.0f) c = 1.0f;
    gv[t] = sums[(size_t)g * HID + t] / c;   // cold path: keep exact division
    __syncthreads();
    float acc = rb1[t];
    for (int k4 = 0; k4 < 32; ++k4) {
        float4 mv = *(const float4*)&gv[k4 * 4];
        #pragma unroll
        for (int j = 0; j < 4; ++j)
            acc += ((const float*)&mv)[j] * rw1[(size_t)(k4 * 4 + j) * HID + t];
    }
    hv[t] = silu_f(acc) * rw2[t];
    __syncthreads();
    for (int s = HID / 2; s > 0; s >>= 1) {
        if (t < s) hv[t] += hv[t + s];
        __syncthreads();
    }
    if (t == 0) pred[g] = hv[0] + rb2[0];
}

extern "C" void kernel_launch(void* const* d_in, const int* in_sizes, int n_in,
                              void* d_out, int out_size, void* d_ws, size_t ws_size,
                              hipStream_t stream) {
    const int*   z          = (const int*)d_in[0];
    const int*   edge_index = (const int*)d_in[1];
    const float* edge_attr  = (const float*)d_in[2];
    const int*   batch      = (const int*)d_in[3];
    const float* emb        = (const float*)d_in[4];
    const float* ew1        = (const float*)d_in[5];
    const float* eb1        = (const float*)d_in[6];
    const float* ew2        = (const float*)d_in[7];
    const float* eb2        = (const float*)d_in[8];
    const float* nw         = (const float*)d_in[9];
    const float* nb         = (const float*)d_in[10];
    const float* rw1        = (const float*)d_in[11];
    const float* rb1        = (const float*)d_in[12];
    const float* rw2        = (const float*)d_in[13];
    const float* rb2        = (const float*)d_in[14];
    float* pred = (float*)d_out;

    const int N = in_sizes[0];
    const int E = in_sizes[1] / 2;
    const int G = out_size;
    const int* srcI = edge_index;
    const int* dstI = edge_index + E;

    char* base = (char*)d_ws;
    size_t off = 0;
    auto carve = [&](size_t bytes) -> char* {
        char* p = base + off;
        off = (off + bytes + 255) & ~(size_t)255;
        return p;
    };
    float* sums   = (float*)carve((size_t)G * HID * sizeof(float));
    float* cnts_g = (float*)carve((size_t)G * sizeof(float));
    u16*   xbA    = (u16*)carve((size_t)N * HID * sizeof(u16));
    u16*   xbB    = (u16*)carve((size_t)N * HID * sizeof(u16));
    float* Y      = (float*)carve((size_t)N * HID * sizeof(float));  // dst-proj
    int*   srcS   = (int*)carve((size_t)(E + 64) * sizeof(int));
    int*   dstS   = (int*)carve((size_t)(E + 64) * sizeof(int));
    u16*   eaS    = (u16*)carve((size_t)(E + 64) * 4 * sizeof(u16));
    int*   rowptr = (int*)carve((size_t)(N + 1) * sizeof(int));
    int*   cursor = (int*)carve((size_t)N * sizeof(int));
    int*   cnt    = (int*)carve((size_t)N * sizeof(int));
    u16*   w1af   = (u16*)carve((size_t)4 * 40 * 512 * sizeof(u16)); // KT=5
    u16*   w1bf   = (u16*)carve((size_t)4 * 32 * 512 * sizeof(u16)); // KT=4
    u16*   w2f    = (u16*)carve((size_t)4 * 32 * 512 * sizeof(u16)); // KT=4
    u16*   nwf    = (u16*)carve((size_t)4 * 64 * 512 * sizeof(u16)); // KT=8

    // ---- fused setup: weight swizzle + zero cnt/cursor/sums/counts ----
    {
        long long total = (long long)T1A + T1B + T2 + T3 + 2LL * N + (long long)G * HID + G;
        int blocks = (int)((total + 255) / 256);
        setup_kernel<<<blocks, 256, 0, stream>>>(ew1, ew2, nw, w1af, w1bf, w2f, nwf,
                                                 cnt, cursor, sums, cnts_g, N, G);
    }

    // ---- CSR build (dst-sorted edges) ----
    hist_kernel<<<(E + 255) / 256, 256, 0, stream>>>(dstI, cnt, E);
    scan_kernel<<<1, 1024, 0, stream>>>(cnt, rowptr, N);
    scatter_kernel<<<(E + 255) / 256, 256, 0, stream>>>(
        srcI, dstI, edge_attr, rowptr, cursor, srcS, dstS, eaS, E);

    // embed + graph counts
    embed_kernel<<<N, HID, 0, stream>>>(z, emb, xbA, batch, cnts_g, N);

    // initial dst-projection for layer 0
    y_kernel<<<(N + 31) / 32, 256, 0, stream>>>(xbA, w1bf, Y, N);

    const int nblk = (N + 31) / 32;
    for (int l = 0; l < 4; ++l) {
        const u16* xi = (l & 1) ? xbB : xbA;
        u16*       xo = (l & 1) ? xbA : xbB;
        const u16* w1b_nxt = w1bf + (size_t)((l + 1) & 3) * 32 * 512; // l=3: dummy
        fused_layer<<<nblk, 512, 0, stream>>>(
            xi, xo, srcS, dstS, eaS, rowptr,
            w1af + (size_t)l * 40 * 512, eb1 + (size_t)l * HID,
            w2f + (size_t)l * 32 * 512, eb2 + (size_t)l * HID,
            Y, w1b_nxt,
            nwf + (size_t)l * 64 * 512, nb + (size_t)l * HID,
            batch, sums, (l == 3) ? 1 : 0, N);
    }

    readout_kernel<<<G, HID, 0, stream>>>(sums, cnts_g, rw1, rb1, rw2, rb2, pred);
}

// Round 5
// 1498.847 us; speedup vs baseline: 1.5543x; 1.5543x over previous
//
#include <hip/hip_runtime.h>
#include <math.h>

#define HID  128
#define EDIM 4

typedef unsigned short u16;
typedef u16    us8   __attribute__((ext_vector_type(8)));
typedef __bf16 bf16x8 __attribute__((ext_vector_type(8)));
typedef float  f32x4 __attribute__((ext_vector_type(4)));

// silu via hw rcp: v_rcp_f32 (~1 ulp) instead of IEEE div (10+ inst w/o fast-math)
__device__ __forceinline__ float silu_f(float v) {
    return v * __builtin_amdgcn_rcpf(1.0f + __expf(-v));
}
__device__ __forceinline__ u16 f2bf(float f) {   // RNE fp32->bf16 (cold paths)
    unsigned u = __float_as_uint(f);
    unsigned r = u + 0x7fffu + ((u >> 16) & 1u);
    return (u16)(r >> 16);
}
__device__ __forceinline__ u16 f2bf_fast(float f) {  // round-half-up, 2 ops (hot)
    return (u16)((__float_as_uint(f) + 0x8000u) >> 16);
}
// pack two fp32 -> one u32 of 2 bf16 (round-half-up)
__device__ __forceinline__ unsigned pack_bf2(float a, float b) {
    return ((__float_as_uint(a) + 0x8000u) >> 16) |
           ((__float_as_uint(b) + 0x8000u) & 0xffff0000u);
}
__device__ __forceinline__ float bf2f(u16 s) {
    return __uint_as_float(((unsigned)s) << 16);
}
__device__ __forceinline__ bf16x8 as_bf(us8 v) {
    return __builtin_bit_cast(bf16x8, v);
}

// ---------------- fused setup: weight swizzle + zero-fills ------------------
// Generalized fragment swizzler: logical k -> source row = k + (k>=split ?
// jump : 0); valid iff row < Kdata. Layer stride Kstride rows.
__device__ __forceinline__ void wfrag_gen(const float* __restrict__ w,
        u16* __restrict__ out, int KT, int Kdata, int Kstride,
        int split, int jump, int idx) {
    int lane = idx & 63;
    int f    = (idx >> 6) % (KT * 8);
    int l    = idx / (64 * KT * 8);
    int kt = f >> 3, nt = f & 7;
    int n  = nt * 16 + (lane & 15);
    int k0 = kt * 32 + ((lane >> 4) * 8);
    us8 v;
    #pragma unroll
    for (int j = 0; j < 8; ++j) {
        int k = k0 + j;
        int row = k + (k >= split ? jump : 0);
        v[j] = (row < Kdata) ? f2bf(w[((size_t)l * Kstride + row) * HID + n]) : (u16)0;
    }
    *(us8*)&out[((size_t)(l * KT * 8 + f) * 64 + lane) * 8] = v;
}

// W1 [260x128] split: w1a (src rows 0..127 + attr rows 256..259 -> KT=5),
// w1b (dst rows 128..255 -> KT=4; consumed by y_kernel / fused node-Y GEMM).
#define T1A (4 * 5 * 8 * 64)
#define T1B (4 * 4 * 8 * 64)
#define T2  (4 * 4 * 8 * 64)
#define T3  (4 * 8 * 8 * 64)

__global__ __launch_bounds__(256) void setup_kernel(
        const float* __restrict__ ew1, const float* __restrict__ ew2,
        const float* __restrict__ nw,
        u16* __restrict__ w1af, u16* __restrict__ w1bf,
        u16* __restrict__ w2f, u16* __restrict__ nwf,
        int* __restrict__ cnt, int* __restrict__ cursor,
        float* __restrict__ sums, float* __restrict__ cnts_g, int N, int G) {
    const int BIG = 1 << 30;
    int idx = blockIdx.x * 256 + threadIdx.x;
    if (idx < T1A) { wfrag_gen(ew1, w1af, 5, 260, 260, 128, 128, idx); return; }
    idx -= T1A;
    if (idx < T1B) { wfrag_gen(ew1, w1bf, 4, 260, 260, 0, 128, idx); return; }
    idx -= T1B;
    if (idx < T2) { wfrag_gen(ew2, w2f, 4, 128, 128, BIG, 0, idx); return; }
    idx -= T2;
    if (idx < T3) { wfrag_gen(nw, nwf, 8, 256, 256, BIG, 0, idx); return; }
    idx -= T3;
    if (idx < N) { cnt[idx] = 0; return; }
    idx -= N;
    if (idx < N) { cursor[idx] = 0; return; }
    idx -= N;
    if (idx < G * HID) { sums[idx] = 0.f; return; }
    idx -= G * HID;
    if (idx < G) { cnts_g[idx] = 0.f; return; }
}

// ---------------- CSR build: hist -> scan -> scatter ------------------------
__global__ __launch_bounds__(256) void hist_kernel(const int* __restrict__ dst,
        int* __restrict__ cnt, int E) {
    int e = blockIdx.x * 256 + threadIdx.x;
    if (e < E) atomicAdd(&cnt[dst[e]], 1);
}

__global__ __launch_bounds__(1024) void scan_kernel(const int* __restrict__ cnt,
        int* __restrict__ rowptr, int n) {
    __shared__ int s[1024];
    const int t = threadIdx.x;
    const int chunk = (n + 1023) >> 10;
    int lo = t * chunk, hi = lo + chunk;
    if (lo > n) lo = n;
    if (hi > n) hi = n;
    int sum = 0;
    for (int i = lo; i < hi; ++i) sum += cnt[i];
    s[t] = sum;
    __syncthreads();
    for (int off = 1; off < 1024; off <<= 1) {
        int v = (t >= off) ? s[t - off] : 0;
        __syncthreads();
        s[t] += v;
        __syncthreads();
    }
    int run = s[t] - sum;
    for (int i = lo; i < hi; ++i) { rowptr[i] = run; run += cnt[i]; }
    if (t == 1023) rowptr[n] = run;
}

__global__ __launch_bounds__(256) void scatter_kernel(const int* __restrict__ src,
        const int* __restrict__ dst, const float* __restrict__ ea,
        const int* __restrict__ rowptr, int* __restrict__ cursor,
        int* __restrict__ srcS, int* __restrict__ dstS, u16* __restrict__ eaS, int E) {
    int e = blockIdx.x * 256 + threadIdx.x;
    if (e >= E) return;
    int d = dst[e];
    int p = rowptr[d] + atomicAdd(&cursor[d], 1);
    srcS[p] = src[e];
    dstS[p] = d;
    const float* q = &ea[(size_t)e * EDIM];
    ushort4 v;
    v.x = f2bf(q[0]); v.y = f2bf(q[1]); v.z = f2bf(q[2]); v.w = f2bf(q[3]);
    *(ushort4*)&eaS[(size_t)p * 4] = v;
}

// embed + zero agg + graph counts (fused)
__global__ __launch_bounds__(HID) void embed_kernel(const int* __restrict__ z,
        const float* __restrict__ emb, u16* __restrict__ xb,
        float* __restrict__ agg, const int* __restrict__ batch,
        float* __restrict__ counts, int n) {
    int i = blockIdx.x;
    if (i >= n) return;
    int t = threadIdx.x;
    xb[(size_t)i * HID + t] = f2bf(emb[(size_t)z[i] * HID + t]);
    agg[(size_t)i * HID + t] = 0.f;
    if (t == 0) unsafeAtomicAdd(&counts[batch[i]], 1.0f);
}

// ---------------- per-node dst-projection: Y = x @ W1b (fp32 out) -----------
// Layer 0 only; layers 1-3 get Y from node_mfma's fused Y-GEMM (identical
// math: same fragment structure, same K order -> bit-identical results).
__global__ __launch_bounds__(256) void y_kernel(
        const u16* __restrict__ xb, const u16* __restrict__ w1bf,
        float* __restrict__ Y, int n) {
    const int t    = threadIdx.x;
    const int i0   = blockIdx.x * 32;
    const int wv   = t >> 6, lane = t & 63;
    const int lrow = lane & 15;
    const int kq   = lane >> 4;
    const int kq8  = kq * 8;

    int iN[2];
    #pragma unroll
    for (int mt = 0; mt < 2; ++mt) {
        int i = i0 + mt * 16 + lrow; if (i >= n) i = n - 1;
        iN[mt] = i;
    }
    f32x4 acc[2][2];
    #pragma unroll
    for (int mt = 0; mt < 2; ++mt)
        #pragma unroll
        for (int nt = 0; nt < 2; ++nt)
            acc[mt][nt] = (f32x4){0.f, 0.f, 0.f, 0.f};

    #pragma unroll
    for (int kt = 0; kt < 4; ++kt) {
        bf16x8 w0 = *(const bf16x8*)&w1bf[((size_t)(kt * 8 + wv * 2 + 0) * 64 + lane) * 8];
        bf16x8 w1 = *(const bf16x8*)&w1bf[((size_t)(kt * 8 + wv * 2 + 1) * 64 + lane) * 8];
        #pragma unroll
        for (int mt = 0; mt < 2; ++mt) {
            bf16x8 a = as_bf(*(const us8*)&xb[(size_t)iN[mt] * HID + kt * 32 + kq8]);
            acc[mt][0] = __builtin_amdgcn_mfma_f32_16x16x32_bf16(w0, a, acc[mt][0], 0, 0, 0);
            acc[mt][1] = __builtin_amdgcn_mfma_f32_16x16x32_bf16(w1, a, acc[mt][1], 0, 0, 0);
        }
    }
    #pragma unroll
    for (int mt = 0; mt < 2; ++mt) {
        int node = i0 + mt * 16 + lrow;
        if (node < n) {
            #pragma unroll
            for (int nt = 0; nt < 2; ++nt)
                *(f32x4*)&Y[(size_t)node * HID + (wv * 2 + nt) * 16 + kq * 4] = acc[mt][nt];
        }
    }
}

// ---------------- edge MLP: 64 dst-sorted edges/block, 8 waves --------------
// R12 core + R15 wave-local scan + R16 (8 waves, swapped MFMA operands) +
// R17 (dst-dedup, K=160). R20 (this round): H gets its OWN LDS region (M
// aliases A only) -> the A->H WAR barrier and H->M WAR barrier vanish.
// 2 barriers/block (post-stage, post-H) instead of 4. Post-H barrier also
// orders all GEMM1 A-reads before M writes (H writes follow GEMM1 in each
// wave's program order). LDS 34304 -> 51456 B (3 blocks/CU, 24 waves/CU —
// R0/R1 showed perf flat over 13..32 waves/CU). Edge math bit-identical.
// FAILED variants (do not reintroduce): R9 XOR-swizzle 32KB (235 us),
// R13 2x2 wave tiling (164 us), R16 occupancy 2x (flat; throughput-bound),
// R18 VGPR-persistent weights (spill, 197 us), R19 node-centric full-layer
// fusion (L2 thrash, FETCH 10x, 840 us).
__global__ __launch_bounds__(512, 8) void edge_mfma(
        const u16* __restrict__ xin, const int* __restrict__ srcS,
        const int* __restrict__ dstS, const u16* __restrict__ eaS,
        const u16* __restrict__ w1af, const float* __restrict__ b1,
        const u16* __restrict__ w2f, const float* __restrict__ b2,
        const float* __restrict__ Y,
        float* __restrict__ agg, int nE) {
    // A: u16 [64][168] = 21504 B  | M: f32 [64][132] = 33792 B (aliases A)
    // H: u16 [64][136] = 17408 B  (separate -> no WAR barriers vs A/M)
    __shared__ __align__(16) char smemM[64 * 132 * 4];
    __shared__ __align__(16) char smemH[64 * 136 * 2];
    __shared__ __align__(16) int dsh[64];
    u16*   A = (u16*)smemM;
    float* M = (float*)smemM;
    u16*   H = (u16*)smemH;

    const int t    = threadIdx.x;
    const int e0   = blockIdx.x * 64;
    const int wv   = t >> 6, lane = t & 63;
    const int lrow = lane & 15;
    const int kq   = lane >> 4;
    const int kq8  = kq * 8;
    const int rq   = kq * 4;
    const int h    = wv >> 2;     // edge-half this wave owns (0/1)
    const int p    = wv & 3;      // col-pair this wave owns (0..3)

    // ---- stage A: 64 rows x 16 src-chunks of 8 bf16 (dst not staged) ----
    #pragma unroll
    for (int it = 0; it < 2; ++it) {
        int slot = it * 512 + t;           // 1024 slots
        int row = slot >> 4, ch = slot & 15;
        int e = e0 + row; if (e >= nE) e = nE - 1;
        int node = srcS[e];
        us8 v = *(const us8*)&xin[(size_t)node * HID + ch * 8];
        *(us8*)&A[row * 168 + ch * 8] = v;
    }
    if (t < 64) {
        int e = e0 + t;
        bool valid = e < nE; if (!valid) e = nE - 1;
        dsh[t] = valid ? dstS[e] : -1;
        ushort4 q = *(const ushort4*)&eaS[(size_t)e * 4];
        int base = t * 168 + 128;
        us8 z8 = (us8){0, 0, 0, 0, 0, 0, 0, 0};
        *(us8*)&A[base + 8]  = z8;         // cols 136..159 zero (K-pad)
        *(us8*)&A[base + 16] = z8;
        *(us8*)&A[base + 24] = z8;
        A[base + 0] = q.x; A[base + 1] = q.y; A[base + 2] = q.z; A[base + 3] = q.w;
        A[base + 4] = 0;   A[base + 5] = 0;   A[base + 6] = 0;   A[base + 7] = 0;
    }
    __syncthreads();

    // ---- GEMM1: K=160 (src+attr). acc init = b1 + Y[dst] (dedup'd dst part).
    //      Lane (lrow,kq) holds n = (p*2+nt)*16 + rq + r, edge = (h*2+mt)*16+lrow.
    f32x4 acc[2][2];
    #pragma unroll
    for (int mt = 0; mt < 2; ++mt) {
        int edge = (h * 2 + mt) * 16 + lrow;
        int d = dsh[edge]; if (d < 0) d = 0;   // tail-safe (unused result)
        #pragma unroll
        for (int nt = 0; nt < 2; ++nt) {
            f32x4 bv = *(const f32x4*)&b1[(p * 2 + nt) * 16 + rq];
            f32x4 yv = *(const f32x4*)&Y[(size_t)d * HID + (p * 2 + nt) * 16 + rq];
            acc[mt][nt] = bv + yv;
        }
    }
    #pragma unroll
    for (int kt = 0; kt < 5; ++kt) {
        bf16x8 w0 = *(const bf16x8*)&w1af[((size_t)(kt * 8 + p * 2 + 0) * 64 + lane) * 8];
        bf16x8 w1 = *(const bf16x8*)&w1af[((size_t)(kt * 8 + p * 2 + 1) * 64 + lane) * 8];
        #pragma unroll
        for (int mt = 0; mt < 2; ++mt) {
            bf16x8 a = *(const bf16x8*)&A[((h * 2 + mt) * 16 + lrow) * 168 + kt * 32 + kq8];
            acc[mt][0] = __builtin_amdgcn_mfma_f32_16x16x32_bf16(w0, a, acc[mt][0], 0, 0, 0);
            acc[mt][1] = __builtin_amdgcn_mfma_f32_16x16x32_bf16(w1, a, acc[mt][1], 0, 0, 0);
        }
    }

    // silu -> H (separate region; no barrier needed after GEMM1)
    #pragma unroll
    for (int mt = 0; mt < 2; ++mt)
        #pragma unroll
        for (int nt = 0; nt < 2; ++nt) {
            uint2 hv;
            hv.x = pack_bf2(silu_f(acc[mt][nt][0]), silu_f(acc[mt][nt][1]));
            hv.y = pack_bf2(silu_f(acc[mt][nt][2]), silu_f(acc[mt][nt][3]));
            int edge = (h * 2 + mt) * 16 + lrow;
            *(uint2*)&H[edge * 136 + (p * 2 + nt) * 16 + rq] = hv;
        }
    __syncthreads();   // H complete; also orders all A reads before M writes

    // ---- GEMM2: [64 x 128] @ [128 x 128], swapped operands ----
    f32x4 acc2[2][2];
    #pragma unroll
    for (int nt = 0; nt < 2; ++nt) {
        f32x4 bv = *(const f32x4*)&b2[(p * 2 + nt) * 16 + rq];
        acc2[0][nt] = bv; acc2[1][nt] = bv;
    }
    #pragma unroll
    for (int kt = 0; kt < 4; ++kt) {
        bf16x8 w0 = *(const bf16x8*)&w2f[((size_t)(kt * 8 + p * 2 + 0) * 64 + lane) * 8];
        bf16x8 w1 = *(const bf16x8*)&w2f[((size_t)(kt * 8 + p * 2 + 1) * 64 + lane) * 8];
        #pragma unroll
        for (int mt = 0; mt < 2; ++mt) {
            bf16x8 a = *(const bf16x8*)&H[((h * 2 + mt) * 16 + lrow) * 136 + kt * 32 + kq8];
            acc2[mt][0] = __builtin_amdgcn_mfma_f32_16x16x32_bf16(w0, a, acc2[mt][0], 0, 0, 0);
            acc2[mt][1] = __builtin_amdgcn_mfma_f32_16x16x32_bf16(w1, a, acc2[mt][1], 0, 0, 0);
        }
    }

    // silu -> M (aliases A only; A reads ordered by post-H barrier; H intact)
    #pragma unroll
    for (int mt = 0; mt < 2; ++mt)
        #pragma unroll
        for (int nt = 0; nt < 2; ++nt) {
            f32x4 mv;
            #pragma unroll
            for (int r = 0; r < 4; ++r) mv[r] = silu_f(acc2[mt][nt][r]);
            int edge = (h * 2 + mt) * 16 + lrow;
            *(f32x4*)&M[edge * 132 + (p * 2 + nt) * 16 + rq] = mv;
        }

    // ---- wave-local segmented reduction: wave (h,p) scans exactly the
    // 32-row x 32-col M region it wrote (NO barrier; intra-wave DS program
    // order + compiler lgkmcnt waits guarantee visibility). dsh preloaded
    // as 4x ds_read_b128.
    {
        int col = p * 32 + (lane & 31);
        int r0  = h * 32 + (lane >> 5) * 16;   // rows r0..r0+15
        int4 da = *(const int4*)&dsh[r0];
        int4 db = *(const int4*)&dsh[r0 + 4];
        int4 dc = *(const int4*)&dsh[r0 + 8];
        int4 dd = *(const int4*)&dsh[r0 + 12];
        int ds_[16] = {da.x, da.y, da.z, da.w, db.x, db.y, db.z, db.w,
                       dc.x, dc.y, dc.z, dc.w, dd.x, dd.y, dd.z, dd.w};
        float run = 0.f;
        int   cur = ds_[0];
        #pragma unroll
        for (int i = 0; i < 16; ++i) {
            run += M[(r0 + i) * 132 + col];
            int nxt = (i == 15) ? -2 : ds_[i + 1];
            if (cur != nxt) {             // uniform within 32-lane half
                if (cur >= 0)
                    unsafeAtomicAdd(&agg[(size_t)cur * HID + col], run);
                run = 0.f; cur = nxt;
            }
        }
    }
}

// ---------------- node MLP: 32 nodes/block + fused next-layer Y-GEMM --------
// R20: swapped operands (mfma(w,a), R4-verified mapping: lane holds node =
// mt*16+lrow, cols (wv*2+nt)*16+rq..+3) -> packed uint2 xb stores (was 16
// scalar b16). Tail fuses next layer's Y = x_new @ W1b_next via an 8 KB LDS
// stage of bf16 x_new — bit-identical math to y_kernel (same fragments,
// same K order, same bf16 inputs). Kills 3 y_kernel launches.
// last==1: scatter silu(acc) into per-graph sums (R4-verified pattern).
__global__ __launch_bounds__(256) void node_mfma(
        u16* __restrict__ xb, float* __restrict__ agg,
        const u16* __restrict__ nwf, const float* __restrict__ nb,
        const int* __restrict__ batch, float* __restrict__ sums,
        float* __restrict__ Y, const u16* __restrict__ w1bf_nxt,
        int last, int n) {
    __shared__ __align__(16) u16 xnS[32 * HID];   // 8 KB
    const int t    = threadIdx.x;
    const int i0   = blockIdx.x * 32;
    const int wv   = t >> 6, lane = t & 63;
    const int lrow = lane & 15;
    const int kq   = lane >> 4;
    const int kq8  = kq * 8;
    const int rq   = kq * 4;

    int iN[2];
    #pragma unroll
    for (int mt = 0; mt < 2; ++mt) {
        int i = i0 + mt * 16 + lrow; if (i >= n) i = n - 1;
        iN[mt] = i;
    }

    f32x4 acc[2][2];
    #pragma unroll
    for (int mt = 0; mt < 2; ++mt)
        #pragma unroll
        for (int nt = 0; nt < 2; ++nt)
            acc[mt][nt] = *(const f32x4*)&nb[(wv * 2 + nt) * 16 + rq];

    #pragma unroll
    for (int kt = 0; kt < 4; ++kt) {     // x part (k 0..127)
        bf16x8 w0 = *(const bf16x8*)&nwf[((size_t)(kt * 8 + wv * 2 + 0) * 64 + lane) * 8];
        bf16x8 w1 = *(const bf16x8*)&nwf[((size_t)(kt * 8 + wv * 2 + 1) * 64 + lane) * 8];
        #pragma unroll
        for (int mt = 0; mt < 2; ++mt) {
            bf16x8 a = as_bf(*(const us8*)&xb[(size_t)iN[mt] * HID + kt * 32 + kq8]);
            acc[mt][0] = __builtin_amdgcn_mfma_f32_16x16x32_bf16(w0, a, acc[mt][0], 0, 0, 0);
            acc[mt][1] = __builtin_amdgcn_mfma_f32_16x16x32_bf16(w1, a, acc[mt][1], 0, 0, 0);
        }
    }
    #pragma unroll
    for (int kt = 4; kt < 8; ++kt) {     // agg part (k 128..255), fp32 -> bf16
        bf16x8 w0 = *(const bf16x8*)&nwf[((size_t)(kt * 8 + wv * 2 + 0) * 64 + lane) * 8];
        bf16x8 w1 = *(const bf16x8*)&nwf[((size_t)(kt * 8 + wv * 2 + 1) * 64 + lane) * 8];
        #pragma unroll
        for (int mt = 0; mt < 2; ++mt) {
            const float* pa = &agg[(size_t)iN[mt] * HID + (kt - 4) * 32 + kq8];
            float4 f0 = *(const float4*)pa;
            float4 f1 = *(const float4*)(pa + 4);
            us8 av;
            av[0] = f2bf_fast(f0.x); av[1] = f2bf_fast(f0.y);
            av[2] = f2bf_fast(f0.z); av[3] = f2bf_fast(f0.w);
            av[4] = f2bf_fast(f1.x); av[5] = f2bf_fast(f1.y);
            av[6] = f2bf_fast(f1.z); av[7] = f2bf_fast(f1.w);
            bf16x8 a = as_bf(av);
            acc[mt][0] = __builtin_amdgcn_mfma_f32_16x16x32_bf16(w0, a, acc[mt][0], 0, 0, 0);
            acc[mt][1] = __builtin_amdgcn_mfma_f32_16x16x32_bf16(w1, a, acc[mt][1], 0, 0, 0);
        }
    }

    if (!last) {
        __syncthreads();   // all xb/agg reads in block complete before overwrite
        const float4 z4 = make_float4(0.f, 0.f, 0.f, 0.f);
        #pragma unroll
        for (int kt = 0; kt < 4; ++kt)
            #pragma unroll
            for (int mt = 0; mt < 2; ++mt) {
                float* pa = &agg[(size_t)iN[mt] * HID + kt * 32 + kq8];
                *(float4*)pa = z4; *(float4*)(pa + 4) = z4;
            }
        // x_new -> xb (packed) + LDS stage for the Y-GEMM
        #pragma unroll
        for (int mt = 0; mt < 2; ++mt) {
            int node = mt * 16 + lrow;
            #pragma unroll
            for (int nt = 0; nt < 2; ++nt) {
                uint2 xv;
                xv.x = pack_bf2(silu_f(acc[mt][nt][0]), silu_f(acc[mt][nt][1]));
                xv.y = pack_bf2(silu_f(acc[mt][nt][2]), silu_f(acc[mt][nt][3]));
                *(uint2*)&xnS[node * HID + (wv * 2 + nt) * 16 + rq] = xv;
                if (i0 + node < n)
                    *(uint2*)&xb[(size_t)(i0 + node) * HID + (wv * 2 + nt) * 16 + rq] = xv;
            }
        }
        __syncthreads();   // xnS complete before cross-wave fragment reads

        // ---- fused Y-GEMM for NEXT layer: Y = x_new @ W1b_next ----
        f32x4 accY[2][2];
        #pragma unroll
        for (int mt = 0; mt < 2; ++mt)
            #pragma unroll
            for (int nt = 0; nt < 2; ++nt)
                accY[mt][nt] = (f32x4){0.f, 0.f, 0.f, 0.f};
        #pragma unroll
        for (int kt = 0; kt < 4; ++kt) {
            bf16x8 w0 = *(const bf16x8*)&w1bf_nxt[((size_t)(kt * 8 + wv * 2 + 0) * 64 + lane) * 8];
            bf16x8 w1 = *(const bf16x8*)&w1bf_nxt[((size_t)(kt * 8 + wv * 2 + 1) * 64 + lane) * 8];
            #pragma unroll
            for (int mt = 0; mt < 2; ++mt) {
                bf16x8 a = as_bf(*(const us8*)&xnS[(mt * 16 + lrow) * HID + kt * 32 + kq8]);
                accY[mt][0] = __builtin_amdgcn_mfma_f32_16x16x32_bf16(w0, a, accY[mt][0], 0, 0, 0);
                accY[mt][1] = __builtin_amdgcn_mfma_f32_16x16x32_bf16(w1, a, accY[mt][1], 0, 0, 0);
            }
        }
        #pragma unroll
        for (int mt = 0; mt < 2; ++mt) {
            int node = mt * 16 + lrow;
            if (i0 + node < n) {
                #pragma unroll
                for (int nt = 0; nt < 2; ++nt)
                    *(f32x4*)&Y[(size_t)(i0 + node) * HID + (wv * 2 + nt) * 16 + rq] =
                        accY[mt][nt];
            }
        }
    } else {
        // final layer: scatter silu straight into per-graph sums
        #pragma unroll
        for (int mt = 0; mt < 2; ++mt) {
            int node = mt * 16 + lrow;
            if (i0 + node < n) {
                int b = batch[i0 + node];
                #pragma unroll
                for (int nt = 0; nt < 2; ++nt)
                    #pragma unroll
                    for (int r = 0; r < 4; ++r)
                        unsafeAtomicAdd(&sums[(size_t)b * HID + (wv * 2 + nt) * 16 + rq + r],
                                        silu_f(acc[mt][nt][r]));
            }
        }
    }
}

// ---------------- readout ---------------------------------------------------
__global__ __launch_bounds__(HID) void readout_kernel(
        const float* __restrict__ sums, const float* __restrict__ counts,
        const float* __restrict__ rw1, const float* __restrict__ rb1,
        const float* __restrict__ rw2, const float* __restrict__ rb2,
        float* __restrict__ pred) {
    __shared__ float gv[HID];
    __shared__ float hv[HID];
    const int g = blockIdx.x;
    const int t = threadIdx.x;
    float c = counts[g];
    if (c < 1.0f) c = 1.0f;
    gv[t] = sums[(size_t)g * HID + t] / c;   // cold path: keep exact division
    __syncthreads();
    float acc = rb1[t];
    for (int k4 = 0; k4 < 32; ++k4) {
        float4 mv = *(const float4*)&gv[k4 * 4];
        #pragma unroll
        for (int j = 0; j < 4; ++j)
            acc += ((const float*)&mv)[j] * rw1[(size_t)(k4 * 4 + j) * HID + t];
    }
    hv[t] = silu_f(acc) * rw2[t];
    __syncthreads();
    for (int s = HID / 2; s > 0; s >>= 1) {
        if (t < s) hv[t] += hv[t + s];
        __syncthreads();
    }
    if (t == 0) pred[g] = hv[0] + rb2[0];
}

extern "C" void kernel_launch(void* const* d_in, const int* in_sizes, int n_in,
                              void* d_out, int out_size, void* d_ws, size_t ws_size,
                              hipStream_t stream) {
    const int*   z          = (const int*)d_in[0];
    const int*   edge_index = (const int*)d_in[1];
    const float* edge_attr  = (const float*)d_in[2];
    const int*   batch      = (const int*)d_in[3];
    const float* emb        = (const float*)d_in[4];
    const float* ew1        = (const float*)d_in[5];
    const float* eb1        = (const float*)d_in[6];
    const float* ew2        = (const float*)d_in[7];
    const float* eb2        = (const float*)d_in[8];
    const float* nw         = (const float*)d_in[9];
    const float* nb         = (const float*)d_in[10];
    const float* rw1        = (const float*)d_in[11];
    const float* rb1        = (const float*)d_in[12];
    const float* rw2        = (const float*)d_in[13];
    const float* rb2        = (const float*)d_in[14];
    float* pred = (float*)d_out;

    const int N = in_sizes[0];
    const int E = in_sizes[1] / 2;
    const int G = out_size;
    const int* srcI = edge_index;
    const int* dstI = edge_index + E;

    char* base = (char*)d_ws;
    size_t off = 0;
    auto carve = [&](size_t bytes) -> char* {
        char* p = base + off;
        off = (off + bytes + 255) & ~(size_t)255;
        return p;
    };
    float* agg    = (float*)carve((size_t)N * HID * sizeof(float));
    float* sums   = (float*)carve((size_t)G * HID * sizeof(float));
    float* cnts_g = (float*)carve((size_t)G * sizeof(float));
    u16*   xb     = (u16*)carve((size_t)N * HID * sizeof(u16));
    float* Y      = (float*)carve((size_t)N * HID * sizeof(float));  // dst-proj
    int*   srcS   = (int*)carve((size_t)(E + 64) * sizeof(int));
    int*   dstS   = (int*)carve((size_t)(E + 64) * sizeof(int));
    u16*   eaS    = (u16*)carve((size_t)(E + 64) * 4 * sizeof(u16));
    int*   rowptr = (int*)carve((size_t)(N + 1) * sizeof(int));
    int*   cursor = (int*)carve((size_t)N * sizeof(int));
    int*   cnt    = (int*)carve((size_t)N * sizeof(int));
    u16*   w1af   = (u16*)carve((size_t)4 * 40 * 512 * sizeof(u16)); // KT=5
    u16*   w1bf   = (u16*)carve((size_t)4 * 32 * 512 * sizeof(u16)); // KT=4
    u16*   w2f    = (u16*)carve((size_t)4 * 32 * 512 * sizeof(u16)); // KT=4
    u16*   nwf    = (u16*)carve((size_t)4 * 64 * 512 * sizeof(u16)); // KT=8

    // ---- fused setup: weight swizzle + zero cnt/cursor/sums/counts ----
    {
        long long total = (long long)T1A + T1B + T2 + T3 + 2LL * N + (long long)G * HID + G;
        int blocks = (int)((total + 255) / 256);
        setup_kernel<<<blocks, 256, 0, stream>>>(ew1, ew2, nw, w1af, w1bf, w2f, nwf,
                                                 cnt, cursor, sums, cnts_g, N, G);
    }

    // ---- CSR build (dst-sorted edges) ----
    hist_kernel<<<(E + 255) / 256, 256, 0, stream>>>(dstI, cnt, E);
    scan_kernel<<<1, 1024, 0, stream>>>(cnt, rowptr, N);
    scatter_kernel<<<(E + 255) / 256, 256, 0, stream>>>(
        srcI, dstI, edge_attr, rowptr, cursor, srcS, dstS, eaS, E);

    // embed + zero agg + graph counts
    embed_kernel<<<N, HID, 0, stream>>>(z, emb, xb, agg, batch, cnts_g, N);

    // initial dst-projection for layer 0 (layers 1-3 fused in node_mfma)
    y_kernel<<<(N + 31) / 32, 256, 0, stream>>>(xb, w1bf, Y, N);

    for (int l = 0; l < 4; ++l) {
        edge_mfma<<<(E + 63) / 64, 512, 0, stream>>>(
            xb, srcS, dstS, eaS,
            w1af + (size_t)l * 40 * 512, eb1 + (size_t)l * HID,
            w2f + (size_t)l * 32 * 512, eb2 + (size_t)l * HID,
            Y, agg, E);
        const u16* w1b_nxt = w1bf + (size_t)((l + 1) & 3) * 32 * 512; // l=3: unused
        node_mfma<<<(N + 31) / 32, 256, 0, stream>>>(
            xb, agg, nwf + (size_t)l * 64 * 512, nb + (size_t)l * HID,
            batch, sums, Y, w1b_nxt, (l == 3) ? 1 : 0, N);
    }

    readout_kernel<<<G, HID, 0, stream>>>(sums, cnts_g, rw1, rb1, rw2, rb2, pred);
}

// Round 6
// 1147.867 us; speedup vs baseline: 2.0295x; 1.3058x over previous
//
#include <hip/hip_runtime.h>
#include <math.h>

#define HID  128
#define EDIM 4

typedef unsigned short u16;
typedef u16    us8   __attribute__((ext_vector_type(8)));
typedef __bf16 bf16x8 __attribute__((ext_vector_type(8)));
typedef float  f32x4 __attribute__((ext_vector_type(4)));

// silu via hw rcp: v_rcp_f32 (~1 ulp) instead of IEEE div (10+ inst w/o fast-math)
__device__ __forceinline__ float silu_f(float v) {
    return v * __builtin_amdgcn_rcpf(1.0f + __expf(-v));
}
__device__ __forceinline__ u16 f2bf(float f) {   // RNE fp32->bf16 (cold paths)
    unsigned u = __float_as_uint(f);
    unsigned r = u + 0x7fffu + ((u >> 16) & 1u);
    return (u16)(r >> 16);
}
__device__ __forceinline__ u16 f2bf_fast(float f) {  // round-half-up, 2 ops (hot)
    return (u16)((__float_as_uint(f) + 0x8000u) >> 16);
}
// pack two fp32 -> one u32 of 2 bf16 (round-half-up)
__device__ __forceinline__ unsigned pack_bf2(float a, float b) {
    return ((__float_as_uint(a) + 0x8000u) >> 16) |
           ((__float_as_uint(b) + 0x8000u) & 0xffff0000u);
}
__device__ __forceinline__ float bf2f(u16 s) {
    return __uint_as_float(((unsigned)s) << 16);
}
__device__ __forceinline__ bf16x8 as_bf(us8 v) {
    return __builtin_bit_cast(bf16x8, v);
}

// ---------------- fused setup: weight swizzle + zero-fills ------------------
// Generalized fragment swizzler: logical k -> source row = k + (k>=split ?
// jump : 0); valid iff row < Kdata. Layer stride Kstride rows.
__device__ __forceinline__ void wfrag_gen(const float* __restrict__ w,
        u16* __restrict__ out, int KT, int Kdata, int Kstride,
        int split, int jump, int idx) {
    int lane = idx & 63;
    int f    = (idx >> 6) % (KT * 8);
    int l    = idx / (64 * KT * 8);
    int kt = f >> 3, nt = f & 7;
    int n  = nt * 16 + (lane & 15);
    int k0 = kt * 32 + ((lane >> 4) * 8);
    us8 v;
    #pragma unroll
    for (int j = 0; j < 8; ++j) {
        int k = k0 + j;
        int row = k + (k >= split ? jump : 0);
        v[j] = (row < Kdata) ? f2bf(w[((size_t)l * Kstride + row) * HID + n]) : (u16)0;
    }
    *(us8*)&out[((size_t)(l * KT * 8 + f) * 64 + lane) * 8] = v;
}

// W1 [260x128] split: w1a (src rows 0..127 + attr rows 256..259 -> KT=5),
// w1b (dst rows 128..255 -> KT=4; consumed by y_kernel).
#define T1A (4 * 5 * 8 * 64)
#define T1B (4 * 4 * 8 * 64)
#define T2  (4 * 4 * 8 * 64)
#define T3  (4 * 8 * 8 * 64)

__global__ __launch_bounds__(256) void setup_kernel(
        const float* __restrict__ ew1, const float* __restrict__ ew2,
        const float* __restrict__ nw,
        u16* __restrict__ w1af, u16* __restrict__ w1bf,
        u16* __restrict__ w2f, u16* __restrict__ nwf,
        int* __restrict__ cnt, int* __restrict__ cursor,
        float* __restrict__ sums, float* __restrict__ cnts_g, int N, int G) {
    const int BIG = 1 << 30;
    int idx = blockIdx.x * 256 + threadIdx.x;
    if (idx < T1A) { wfrag_gen(ew1, w1af, 5, 260, 260, 128, 128, idx); return; }
    idx -= T1A;
    if (idx < T1B) { wfrag_gen(ew1, w1bf, 4, 260, 260, 0, 128, idx); return; }
    idx -= T1B;
    if (idx < T2) { wfrag_gen(ew2, w2f, 4, 128, 128, BIG, 0, idx); return; }
    idx -= T2;
    if (idx < T3) { wfrag_gen(nw, nwf, 8, 256, 256, BIG, 0, idx); return; }
    idx -= T3;
    if (idx < N) { cnt[idx] = 0; return; }
    idx -= N;
    if (idx < N) { cursor[idx] = 0; return; }
    idx -= N;
    if (idx < G * HID) { sums[idx] = 0.f; return; }
    idx -= G * HID;
    if (idx < G) { cnts_g[idx] = 0.f; return; }
}

// ---------------- CSR build: hist -> scan -> scatter ------------------------
__global__ __launch_bounds__(256) void hist_kernel(const int* __restrict__ dst,
        int* __restrict__ cnt, int E) {
    int e = blockIdx.x * 256 + threadIdx.x;
    if (e < E) atomicAdd(&cnt[dst[e]], 1);
}

__global__ __launch_bounds__(1024) void scan_kernel(const int* __restrict__ cnt,
        int* __restrict__ rowptr, int n) {
    __shared__ int s[1024];
    const int t = threadIdx.x;
    const int chunk = (n + 1023) >> 10;
    int lo = t * chunk, hi = lo + chunk;
    if (lo > n) lo = n;
    if (hi > n) hi = n;
    int sum = 0;
    for (int i = lo; i < hi; ++i) sum += cnt[i];
    s[t] = sum;
    __syncthreads();
    for (int off = 1; off < 1024; off <<= 1) {
        int v = (t >= off) ? s[t - off] : 0;
        __syncthreads();
        s[t] += v;
        __syncthreads();
    }
    int run = s[t] - sum;
    for (int i = lo; i < hi; ++i) { rowptr[i] = run; run += cnt[i]; }
    if (t == 1023) rowptr[n] = run;
}

__global__ __launch_bounds__(256) void scatter_kernel(const int* __restrict__ src,
        const int* __restrict__ dst, const float* __restrict__ ea,
        const int* __restrict__ rowptr, int* __restrict__ cursor,
        int* __restrict__ srcS, int* __restrict__ dstS, u16* __restrict__ eaS, int E) {
    int e = blockIdx.x * 256 + threadIdx.x;
    if (e >= E) return;
    int d = dst[e];
    int p = rowptr[d] + atomicAdd(&cursor[d], 1);
    srcS[p] = src[e];
    dstS[p] = d;
    const float* q = &ea[(size_t)e * EDIM];
    ushort4 v;
    v.x = f2bf(q[0]); v.y = f2bf(q[1]); v.z = f2bf(q[2]); v.w = f2bf(q[3]);
    *(ushort4*)&eaS[(size_t)p * 4] = v;
}

// embed + zero agg + graph counts (fused)
__global__ __launch_bounds__(HID) void embed_kernel(const int* __restrict__ z,
        const float* __restrict__ emb, u16* __restrict__ xb,
        float* __restrict__ agg, const int* __restrict__ batch,
        float* __restrict__ counts, int n) {
    int i = blockIdx.x;
    if (i >= n) return;
    int t = threadIdx.x;
    xb[(size_t)i * HID + t] = f2bf(emb[(size_t)z[i] * HID + t]);
    agg[(size_t)i * HID + t] = 0.f;
    if (t == 0) unsafeAtomicAdd(&counts[batch[i]], 1.0f);
}

// ---------------- per-node dst-projection: Y = x @ W1b (fp32 out) -----------
// Hoists the x_dst half of edge GEMM1 (avg degree 16 -> 16x dedup). fp32
// output => pure fp32 reassociation vs fused GEMM, no added quantization.
__global__ __launch_bounds__(256) void y_kernel(
        const u16* __restrict__ xb, const u16* __restrict__ w1bf,
        float* __restrict__ Y, int n) {
    const int t    = threadIdx.x;
    const int i0   = blockIdx.x * 32;
    const int wv   = t >> 6, lane = t & 63;
    const int lrow = lane & 15;
    const int kq   = lane >> 4;
    const int kq8  = kq * 8;

    int iN[2];
    #pragma unroll
    for (int mt = 0; mt < 2; ++mt) {
        int i = i0 + mt * 16 + lrow; if (i >= n) i = n - 1;
        iN[mt] = i;
    }
    f32x4 acc[2][2];
    #pragma unroll
    for (int mt = 0; mt < 2; ++mt)
        #pragma unroll
        for (int nt = 0; nt < 2; ++nt)
            acc[mt][nt] = (f32x4){0.f, 0.f, 0.f, 0.f};

    #pragma unroll
    for (int kt = 0; kt < 4; ++kt) {
        bf16x8 w0 = *(const bf16x8*)&w1bf[((size_t)(kt * 8 + wv * 2 + 0) * 64 + lane) * 8];
        bf16x8 w1 = *(const bf16x8*)&w1bf[((size_t)(kt * 8 + wv * 2 + 1) * 64 + lane) * 8];
        #pragma unroll
        for (int mt = 0; mt < 2; ++mt) {
            bf16x8 a = as_bf(*(const us8*)&xb[(size_t)iN[mt] * HID + kt * 32 + kq8]);
            acc[mt][0] = __builtin_amdgcn_mfma_f32_16x16x32_bf16(w0, a, acc[mt][0], 0, 0, 0);
            acc[mt][1] = __builtin_amdgcn_mfma_f32_16x16x32_bf16(w1, a, acc[mt][1], 0, 0, 0);
        }
    }
    // swapped-operand layout: lane holds Y[node=i0+mt*16+lrow][n=(wv*2+nt)*16+kq*4 ..+3]
    #pragma unroll
    for (int mt = 0; mt < 2; ++mt) {
        int node = i0 + mt * 16 + lrow;
        if (node < n) {
            #pragma unroll
            for (int nt = 0; nt < 2; ++nt)
                *(f32x4*)&Y[(size_t)node * HID + (wv * 2 + nt) * 16 + kq * 4] = acc[mt][nt];
        }
    }
}

// ---------------- edge MLP: 64 dst-sorted edges/block, 8 waves --------------
// R12 core + R15 wave-local scan + R16 (8 waves, swapped MFMA operands) +
// R17 (dst-dedup, K=160) + R20 (H in its OWN LDS region; M aliases A only
// -> A->H and H->M WAR barriers removed; 2 barriers/block). Post-H barrier
// also orders all GEMM1 A-reads before M writes. LDS 51456 B (3 blocks/CU,
// 24 waves/CU). Edge math bit-identical to R17.
// FAILED variants (do not reintroduce): R9 XOR-swizzle 32KB (235 us),
// R13 2x2 wave tiling (164 us), R16 occupancy 2x (flat; throughput-bound),
// R18 VGPR-persistent weights (spill, 197 us), R19 node-centric full-layer
// fusion (L2 thrash, FETCH 10x, 840 us), R21/R5 fused node tail (swapped
// stores + xnS + Y-GEMM in node_mfma: node 35->470 us, WRITE 174MB,
// pipes idle — mechanism unresolved, isolate before retry).
__global__ __launch_bounds__(512, 8) void edge_mfma(
        const u16* __restrict__ xin, const int* __restrict__ srcS,
        const int* __restrict__ dstS, const u16* __restrict__ eaS,
        const u16* __restrict__ w1af, const float* __restrict__ b1,
        const u16* __restrict__ w2f, const float* __restrict__ b2,
        const float* __restrict__ Y,
        float* __restrict__ agg, int nE) {
    // A: u16 [64][168] = 21504 B  | M: f32 [64][132] = 33792 B (aliases A)
    // H: u16 [64][136] = 17408 B  (separate -> no WAR barriers vs A/M)
    __shared__ __align__(16) char smemM[64 * 132 * 4];
    __shared__ __align__(16) char smemH[64 * 136 * 2];
    __shared__ __align__(16) int dsh[64];
    u16*   A = (u16*)smemM;
    float* M = (float*)smemM;
    u16*   H = (u16*)smemH;

    const int t    = threadIdx.x;
    const int e0   = blockIdx.x * 64;
    const int wv   = t >> 6, lane = t & 63;
    const int lrow = lane & 15;
    const int kq   = lane >> 4;
    const int kq8  = kq * 8;
    const int rq   = kq * 4;
    const int h    = wv >> 2;     // edge-half this wave owns (0/1)
    const int p    = wv & 3;      // col-pair this wave owns (0..3)

    // ---- stage A: 64 rows x 16 src-chunks of 8 bf16 (dst not staged) ----
    #pragma unroll
    for (int it = 0; it < 2; ++it) {
        int slot = it * 512 + t;           // 1024 slots
        int row = slot >> 4, ch = slot & 15;
        int e = e0 + row; if (e >= nE) e = nE - 1;
        int node = srcS[e];
        us8 v = *(const us8*)&xin[(size_t)node * HID + ch * 8];
        *(us8*)&A[row * 168 + ch * 8] = v;
    }
    if (t < 64) {
        int e = e0 + t;
        bool valid = e < nE; if (!valid) e = nE - 1;
        dsh[t] = valid ? dstS[e] : -1;
        ushort4 q = *(const ushort4*)&eaS[(size_t)e * 4];
        int base = t * 168 + 128;
        us8 z8 = (us8){0, 0, 0, 0, 0, 0, 0, 0};
        *(us8*)&A[base + 8]  = z8;         // cols 136..159 zero (K-pad)
        *(us8*)&A[base + 16] = z8;
        *(us8*)&A[base + 24] = z8;
        A[base + 0] = q.x; A[base + 1] = q.y; A[base + 2] = q.z; A[base + 3] = q.w;
        A[base + 4] = 0;   A[base + 5] = 0;   A[base + 6] = 0;   A[base + 7] = 0;
    }
    __syncthreads();

    // ---- GEMM1: K=160 (src+attr). acc init = b1 + Y[dst] (dedup'd dst part).
    //      Lane (lrow,kq) holds n = (p*2+nt)*16 + rq + r, edge = (h*2+mt)*16+lrow.
    f32x4 acc[2][2];
    #pragma unroll
    for (int mt = 0; mt < 2; ++mt) {
        int edge = (h * 2 + mt) * 16 + lrow;
        int d = dsh[edge]; if (d < 0) d = 0;   // tail-safe (unused result)
        #pragma unroll
        for (int nt = 0; nt < 2; ++nt) {
            f32x4 bv = *(const f32x4*)&b1[(p * 2 + nt) * 16 + rq];
            f32x4 yv = *(const f32x4*)&Y[(size_t)d * HID + (p * 2 + nt) * 16 + rq];
            acc[mt][nt] = bv + yv;
        }
    }
    #pragma unroll
    for (int kt = 0; kt < 5; ++kt) {
        bf16x8 w0 = *(const bf16x8*)&w1af[((size_t)(kt * 8 + p * 2 + 0) * 64 + lane) * 8];
        bf16x8 w1 = *(const bf16x8*)&w1af[((size_t)(kt * 8 + p * 2 + 1) * 64 + lane) * 8];
        #pragma unroll
        for (int mt = 0; mt < 2; ++mt) {
            bf16x8 a = *(const bf16x8*)&A[((h * 2 + mt) * 16 + lrow) * 168 + kt * 32 + kq8];
            acc[mt][0] = __builtin_amdgcn_mfma_f32_16x16x32_bf16(w0, a, acc[mt][0], 0, 0, 0);
            acc[mt][1] = __builtin_amdgcn_mfma_f32_16x16x32_bf16(w1, a, acc[mt][1], 0, 0, 0);
        }
    }

    // silu -> H (separate region; no barrier needed after GEMM1)
    #pragma unroll
    for (int mt = 0; mt < 2; ++mt)
        #pragma unroll
        for (int nt = 0; nt < 2; ++nt) {
            uint2 hv;
            hv.x = pack_bf2(silu_f(acc[mt][nt][0]), silu_f(acc[mt][nt][1]));
            hv.y = pack_bf2(silu_f(acc[mt][nt][2]), silu_f(acc[mt][nt][3]));
            int edge = (h * 2 + mt) * 16 + lrow;
            *(uint2*)&H[edge * 136 + (p * 2 + nt) * 16 + rq] = hv;
        }
    __syncthreads();   // H complete; also orders all A reads before M writes

    // ---- GEMM2: [64 x 128] @ [128 x 128], swapped operands ----
    f32x4 acc2[2][2];
    #pragma unroll
    for (int nt = 0; nt < 2; ++nt) {
        f32x4 bv = *(const f32x4*)&b2[(p * 2 + nt) * 16 + rq];
        acc2[0][nt] = bv; acc2[1][nt] = bv;
    }
    #pragma unroll
    for (int kt = 0; kt < 4; ++kt) {
        bf16x8 w0 = *(const bf16x8*)&w2f[((size_t)(kt * 8 + p * 2 + 0) * 64 + lane) * 8];
        bf16x8 w1 = *(const bf16x8*)&w2f[((size_t)(kt * 8 + p * 2 + 1) * 64 + lane) * 8];
        #pragma unroll
        for (int mt = 0; mt < 2; ++mt) {
            bf16x8 a = *(const bf16x8*)&H[((h * 2 + mt) * 16 + lrow) * 136 + kt * 32 + kq8];
            acc2[mt][0] = __builtin_amdgcn_mfma_f32_16x16x32_bf16(w0, a, acc2[mt][0], 0, 0, 0);
            acc2[mt][1] = __builtin_amdgcn_mfma_f32_16x16x32_bf16(w1, a, acc2[mt][1], 0, 0, 0);
        }
    }

    // silu -> M (aliases A only; A reads ordered by post-H barrier; H intact)
    #pragma unroll
    for (int mt = 0; mt < 2; ++mt)
        #pragma unroll
        for (int nt = 0; nt < 2; ++nt) {
            f32x4 mv;
            #pragma unroll
            for (int r = 0; r < 4; ++r) mv[r] = silu_f(acc2[mt][nt][r]);
            int edge = (h * 2 + mt) * 16 + lrow;
            *(f32x4*)&M[edge * 132 + (p * 2 + nt) * 16 + rq] = mv;
        }

    // ---- wave-local segmented reduction: wave (h,p) scans exactly the
    // 32-row x 32-col M region it wrote (NO barrier; intra-wave DS program
    // order + compiler lgkmcnt waits guarantee visibility). dsh preloaded
    // as 4x ds_read_b128.
    {
        int col = p * 32 + (lane & 31);
        int r0  = h * 32 + (lane >> 5) * 16;   // rows r0..r0+15
        int4 da = *(const int4*)&dsh[r0];
        int4 db = *(const int4*)&dsh[r0 + 4];
        int4 dc = *(const int4*)&dsh[r0 + 8];
        int4 dd = *(const int4*)&dsh[r0 + 12];
        int ds_[16] = {da.x, da.y, da.z, da.w, db.x, db.y, db.z, db.w,
                       dc.x, dc.y, dc.z, dc.w, dd.x, dd.y, dd.z, dd.w};
        float run = 0.f;
        int   cur = ds_[0];
        #pragma unroll
        for (int i = 0; i < 16; ++i) {
            run += M[(r0 + i) * 132 + col];
            int nxt = (i == 15) ? -2 : ds_[i + 1];
            if (cur != nxt) {             // uniform within 32-lane half
                if (cur >= 0)
                    unsafeAtomicAdd(&agg[(size_t)cur * HID + col], run);
                run = 0.f; cur = nxt;
            }
        }
    }
}

// ---------------- node MLP: 32 nodes/block (R2-exact, proven fast) ----------
// last==0: x = silu([x|agg]@nw+nb) in place, then zero own agg cells.
// last==1: scatter silu(...) directly into per-graph sums (no x store).
__global__ __launch_bounds__(256) void node_mfma(
        u16* __restrict__ xb, float* __restrict__ agg,
        const u16* __restrict__ nwf, const float* __restrict__ nb,
        const int* __restrict__ batch, float* __restrict__ sums,
        int last, int n) {
    const int t    = threadIdx.x;
    const int i0   = blockIdx.x * 32;
    const int wv   = t >> 6, lane = t & 63;
    const int lrow = lane & 15;
    const int kq   = lane >> 4;
    const int kq8  = kq * 8;
    const int rq   = kq * 4;

    int iN[2];
    #pragma unroll
    for (int mt = 0; mt < 2; ++mt) {
        int i = i0 + mt * 16 + lrow; if (i >= n) i = n - 1;
        iN[mt] = i;
    }

    f32x4 acc[2][2];
    {
        float bias0 = nb[wv * 32 + lrow], bias1 = nb[wv * 32 + 16 + lrow];
        #pragma unroll
        for (int mt = 0; mt < 2; ++mt)
            #pragma unroll
            for (int r = 0; r < 4; ++r) {
                acc[mt][0][r] = bias0; acc[mt][1][r] = bias1;
            }
    }
    #pragma unroll
    for (int kt = 0; kt < 4; ++kt) {     // x part (k 0..127)
        bf16x8 w0 = *(const bf16x8*)&nwf[((size_t)(kt * 8 + wv * 2 + 0) * 64 + lane) * 8];
        bf16x8 w1 = *(const bf16x8*)&nwf[((size_t)(kt * 8 + wv * 2 + 1) * 64 + lane) * 8];
        #pragma unroll
        for (int mt = 0; mt < 2; ++mt) {
            bf16x8 a = as_bf(*(const us8*)&xb[(size_t)iN[mt] * HID + kt * 32 + kq8]);
            acc[mt][0] = __builtin_amdgcn_mfma_f32_16x16x32_bf16(a, w0, acc[mt][0], 0, 0, 0);
            acc[mt][1] = __builtin_amdgcn_mfma_f32_16x16x32_bf16(a, w1, acc[mt][1], 0, 0, 0);
        }
    }
    #pragma unroll
    for (int kt = 4; kt < 8; ++kt) {     // agg part (k 128..255), fp32 -> bf16
        bf16x8 w0 = *(const bf16x8*)&nwf[((size_t)(kt * 8 + wv * 2 + 0) * 64 + lane) * 8];
        bf16x8 w1 = *(const bf16x8*)&nwf[((size_t)(kt * 8 + wv * 2 + 1) * 64 + lane) * 8];
        #pragma unroll
        for (int mt = 0; mt < 2; ++mt) {
            const float* pa = &agg[(size_t)iN[mt] * HID + (kt - 4) * 32 + kq8];
            float4 f0 = *(const float4*)pa;
            float4 f1 = *(const float4*)(pa + 4);
            us8 av;
            av[0] = f2bf_fast(f0.x); av[1] = f2bf_fast(f0.y);
            av[2] = f2bf_fast(f0.z); av[3] = f2bf_fast(f0.w);
            av[4] = f2bf_fast(f1.x); av[5] = f2bf_fast(f1.y);
            av[6] = f2bf_fast(f1.z); av[7] = f2bf_fast(f1.w);
            bf16x8 a = as_bf(av);
            acc[mt][0] = __builtin_amdgcn_mfma_f32_16x16x32_bf16(a, w0, acc[mt][0], 0, 0, 0);
            acc[mt][1] = __builtin_amdgcn_mfma_f32_16x16x32_bf16(a, w1, acc[mt][1], 0, 0, 0);
        }
    }

    if (!last) {
        __syncthreads();   // all xb/agg reads in block complete before overwrite
        const float4 z4 = make_float4(0.f, 0.f, 0.f, 0.f);
        #pragma unroll
        for (int kt = 0; kt < 4; ++kt)
            #pragma unroll
            for (int mt = 0; mt < 2; ++mt) {
                float* pa = &agg[(size_t)iN[mt] * HID + kt * 32 + kq8];
                *(float4*)pa = z4; *(float4*)(pa + 4) = z4;
            }
        #pragma unroll
        for (int mt = 0; mt < 2; ++mt)
            #pragma unroll
            for (int nt2 = 0; nt2 < 2; ++nt2)
                #pragma unroll
                for (int r = 0; r < 4; ++r) {
                    int i = i0 + mt * 16 + rq + r;
                    if (i < n)
                        xb[(size_t)i * HID + wv * 32 + nt2 * 16 + lrow] =
                            f2bf_fast(silu_f(acc[mt][nt2][r]));
                }
    } else {
        // final layer: scatter straight into per-graph sums
        #pragma unroll
        for (int mt = 0; mt < 2; ++mt)
            #pragma unroll
            for (int nt2 = 0; nt2 < 2; ++nt2)
                #pragma unroll
                for (int r = 0; r < 4; ++r) {
                    int i = i0 + mt * 16 + rq + r;
                    if (i < n) {
                        int b = batch[i];
                        unsafeAtomicAdd(&sums[(size_t)b * HID + wv * 32 + nt2 * 16 + lrow],
                                        silu_f(acc[mt][nt2][r]));
                    }
                }
    }
}

// ---------------- readout ---------------------------------------------------
__global__ __launch_bounds__(HID) void readout_kernel(
        const float* __restrict__ sums, const float* __restrict__ counts,
        const float* __restrict__ rw1, const float* __restrict__ rb1,
        const float* __restrict__ rw2, const float* __restrict__ rb2,
        float* __restrict__ pred) {
    __shared__ float gv[HID];
    __shared__ float hv[HID];
    const int g = blockIdx.x;
    const int t = threadIdx.x;
    float c = counts[g];
    if (c < 1.0f) c = 1.0f;
    gv[t] = sums[(size_t)g * HID + t] / c;   // cold path: keep exact division
    __syncthreads();
    float acc = rb1[t];
    for (int k4 = 0; k4 < 32; ++k4) {
        float4 mv = *(const float4*)&gv[k4 * 4];
        #pragma unroll
        for (int j = 0; j < 4; ++j)
            acc += ((const float*)&mv)[j] * rw1[(size_t)(k4 * 4 + j) * HID + t];
    }
    hv[t] = silu_f(acc) * rw2[t];
    __syncthreads();
    for (int s = HID / 2; s > 0; s >>= 1) {
        if (t < s) hv[t] += hv[t + s];
        __syncthreads();
    }
    if (t == 0) pred[g] = hv[0] + rb2[0];
}

extern "C" void kernel_launch(void* const* d_in, const int* in_sizes, int n_in,
                              void* d_out, int out_size, void* d_ws, size_t ws_size,
                              hipStream_t stream) {
    const int*   z          = (const int*)d_in[0];
    const int*   edge_index = (const int*)d_in[1];
    const float* edge_attr  = (const float*)d_in[2];
    const int*   batch      = (const int*)d_in[3];
    const float* emb        = (const float*)d_in[4];
    const float* ew1        = (const float*)d_in[5];
    const float* eb1        = (const float*)d_in[6];
    const float* ew2        = (const float*)d_in[7];
    const float* eb2        = (const float*)d_in[8];
    const float* nw         = (const float*)d_in[9];
    const float* nb         = (const float*)d_in[10];
    const float* rw1        = (const float*)d_in[11];
    const float* rb1        = (const float*)d_in[12];
    const float* rw2        = (const float*)d_in[13];
    const float* rb2        = (const float*)d_in[14];
    float* pred = (float*)d_out;

    const int N = in_sizes[0];
    const int E = in_sizes[1] / 2;
    const int G = out_size;
    const int* srcI = edge_index;
    const int* dstI = edge_index + E;

    char* base = (char*)d_ws;
    size_t off = 0;
    auto carve = [&](size_t bytes) -> char* {
        char* p = base + off;
        off = (off + bytes + 255) & ~(size_t)255;
        return p;
    };
    float* agg    = (float*)carve((size_t)N * HID * sizeof(float));
    float* sums   = (float*)carve((size_t)G * HID * sizeof(float));
    float* cnts_g = (float*)carve((size_t)G * sizeof(float));
    u16*   xb     = (u16*)carve((size_t)N * HID * sizeof(u16));
    float* Y      = (float*)carve((size_t)N * HID * sizeof(float));  // dst-proj
    int*   srcS   = (int*)carve((size_t)(E + 64) * sizeof(int));
    int*   dstS   = (int*)carve((size_t)(E + 64) * sizeof(int));
    u16*   eaS    = (u16*)carve((size_t)(E + 64) * 4 * sizeof(u16));
    int*   rowptr = (int*)carve((size_t)(N + 1) * sizeof(int));
    int*   cursor = (int*)carve((size_t)N * sizeof(int));
    int*   cnt    = (int*)carve((size_t)N * sizeof(int));
    u16*   w1af   = (u16*)carve((size_t)4 * 40 * 512 * sizeof(u16)); // KT=5
    u16*   w1bf   = (u16*)carve((size_t)4 * 32 * 512 * sizeof(u16)); // KT=4
    u16*   w2f    = (u16*)carve((size_t)4 * 32 * 512 * sizeof(u16)); // KT=4
    u16*   nwf    = (u16*)carve((size_t)4 * 64 * 512 * sizeof(u16)); // KT=8

    // ---- fused setup: weight swizzle + zero cnt/cursor/sums/counts ----
    {
        long long total = (long long)T1A + T1B + T2 + T3 + 2LL * N + (long long)G * HID + G;
        int blocks = (int)((total + 255) / 256);
        setup_kernel<<<blocks, 256, 0, stream>>>(ew1, ew2, nw, w1af, w1bf, w2f, nwf,
                                                 cnt, cursor, sums, cnts_g, N, G);
    }

    // ---- CSR build (dst-sorted edges) ----
    hist_kernel<<<(E + 255) / 256, 256, 0, stream>>>(dstI, cnt, E);
    scan_kernel<<<1, 1024, 0, stream>>>(cnt, rowptr, N);
    scatter_kernel<<<(E + 255) / 256, 256, 0, stream>>>(
        srcI, dstI, edge_attr, rowptr, cursor, srcS, dstS, eaS, E);

    // embed + zero agg + graph counts
    embed_kernel<<<N, HID, 0, stream>>>(z, emb, xb, agg, batch, cnts_g, N);

    for (int l = 0; l < 4; ++l) {
        y_kernel<<<(N + 31) / 32, 256, 0, stream>>>(
            xb, w1bf + (size_t)l * 32 * 512, Y, N);
        edge_mfma<<<(E + 63) / 64, 512, 0, stream>>>(
            xb, srcS, dstS, eaS,
            w1af + (size_t)l * 40 * 512, eb1 + (size_t)l * HID,
            w2f + (size_t)l * 32 * 512, eb2 + (size_t)l * HID,
            Y, agg, E);
        node_mfma<<<(N + 31) / 32, 256, 0, stream>>>(
            xb, agg, nwf + (size_t)l * 64 * 512, nb + (size_t)l * HID,
            batch, sums, (l == 3) ? 1 : 0, N);
    }

    readout_kernel<<<G, HID, 0, stream>>>(sums, cnts_g, rw1, rb1, rw2, rb2, pred);
}

// Round 7
// 1124.450 us; speedup vs baseline: 2.0718x; 1.0208x over previous
//
#include <hip/hip_runtime.h>
#include <math.h>

#define HID  128
#define EDIM 4

typedef unsigned short u16;
typedef u16    us8   __attribute__((ext_vector_type(8)));
typedef __bf16 bf16x8 __attribute__((ext_vector_type(8)));
typedef float  f32x4 __attribute__((ext_vector_type(4)));

// silu via hw rcp: v_rcp_f32 (~1 ulp) instead of IEEE div (10+ inst w/o fast-math)
__device__ __forceinline__ float silu_f(float v) {
    return v * __builtin_amdgcn_rcpf(1.0f + __expf(-v));
}
__device__ __forceinline__ u16 f2bf(float f) {   // RNE fp32->bf16 (cold paths)
    unsigned u = __float_as_uint(f);
    unsigned r = u + 0x7fffu + ((u >> 16) & 1u);
    return (u16)(r >> 16);
}
__device__ __forceinline__ u16 f2bf_fast(float f) {  // round-half-up, 2 ops (hot)
    return (u16)((__float_as_uint(f) + 0x8000u) >> 16);
}
// pack two fp32 -> one u32 of 2 bf16 (round-half-up)
__device__ __forceinline__ unsigned pack_bf2(float a, float b) {
    return ((__float_as_uint(a) + 0x8000u) >> 16) |
           ((__float_as_uint(b) + 0x8000u) & 0xffff0000u);
}
__device__ __forceinline__ float bf2f(u16 s) {
    return __uint_as_float(((unsigned)s) << 16);
}
__device__ __forceinline__ bf16x8 as_bf(us8 v) {
    return __builtin_bit_cast(bf16x8, v);
}

// ---------------- fused setup: weight swizzle + zero-fills ------------------
// Generalized fragment swizzler: logical k -> source row = k + (k>=split ?
// jump : 0); valid iff row < Kdata. Layer stride Kstride rows.
__device__ __forceinline__ void wfrag_gen(const float* __restrict__ w,
        u16* __restrict__ out, int KT, int Kdata, int Kstride,
        int split, int jump, int idx) {
    int lane = idx & 63;
    int f    = (idx >> 6) % (KT * 8);
    int l    = idx / (64 * KT * 8);
    int kt = f >> 3, nt = f & 7;
    int n  = nt * 16 + (lane & 15);
    int k0 = kt * 32 + ((lane >> 4) * 8);
    us8 v;
    #pragma unroll
    for (int j = 0; j < 8; ++j) {
        int k = k0 + j;
        int row = k + (k >= split ? jump : 0);
        v[j] = (row < Kdata) ? f2bf(w[((size_t)l * Kstride + row) * HID + n]) : (u16)0;
    }
    *(us8*)&out[((size_t)(l * KT * 8 + f) * 64 + lane) * 8] = v;
}

// R22 split of W1 [260x128]: w1s (src rows 0..127, KT=4 -> ys_kernel),
// w1b (dst rows 128..255, KT=4 -> ys_kernel), w1t (attr rows 256..259
// zero-padded to K=32, KT=1 -> edge kernel).
#define T1S (4 * 4 * 8 * 64)
#define T1T (4 * 1 * 8 * 64)
#define T1B (4 * 4 * 8 * 64)
#define T2  (4 * 4 * 8 * 64)
#define T3  (4 * 8 * 8 * 64)

__global__ __launch_bounds__(256) void setup_kernel(
        const float* __restrict__ ew1, const float* __restrict__ ew2,
        const float* __restrict__ nw,
        u16* __restrict__ w1sf, u16* __restrict__ w1tf,
        u16* __restrict__ w1bf,
        u16* __restrict__ w2f, u16* __restrict__ nwf,
        int* __restrict__ cnt, int* __restrict__ cursor,
        float* __restrict__ sums, float* __restrict__ cnts_g, int N, int G) {
    const int BIG = 1 << 30;
    int idx = blockIdx.x * 256 + threadIdx.x;
    if (idx < T1S) { wfrag_gen(ew1, w1sf, 4, 128, 260, BIG, 0, idx); return; }
    idx -= T1S;
    if (idx < T1T) { wfrag_gen(ew1, w1tf, 1, 260, 260, 0, 256, idx); return; }
    idx -= T1T;
    if (idx < T1B) { wfrag_gen(ew1, w1bf, 4, 260, 260, 0, 128, idx); return; }
    idx -= T1B;
    if (idx < T2) { wfrag_gen(ew2, w2f, 4, 128, 128, BIG, 0, idx); return; }
    idx -= T2;
    if (idx < T3) { wfrag_gen(nw, nwf, 8, 256, 256, BIG, 0, idx); return; }
    idx -= T3;
    if (idx < N) { cnt[idx] = 0; return; }
    idx -= N;
    if (idx < N) { cursor[idx] = 0; return; }
    idx -= N;
    if (idx < G * HID) { sums[idx] = 0.f; return; }
    idx -= G * HID;
    if (idx < G) { cnts_g[idx] = 0.f; return; }
}

// ---------------- CSR build: hist -> scan -> scatter ------------------------
__global__ __launch_bounds__(256) void hist_kernel(const int* __restrict__ dst,
        int* __restrict__ cnt, int E) {
    int e = blockIdx.x * 256 + threadIdx.x;
    if (e < E) atomicAdd(&cnt[dst[e]], 1);
}

__global__ __launch_bounds__(1024) void scan_kernel(const int* __restrict__ cnt,
        int* __restrict__ rowptr, int n) {
    __shared__ int s[1024];
    const int t = threadIdx.x;
    const int chunk = (n + 1023) >> 10;
    int lo = t * chunk, hi = lo + chunk;
    if (lo > n) lo = n;
    if (hi > n) hi = n;
    int sum = 0;
    for (int i = lo; i < hi; ++i) sum += cnt[i];
    s[t] = sum;
    __syncthreads();
    for (int off = 1; off < 1024; off <<= 1) {
        int v = (t >= off) ? s[t - off] : 0;
        __syncthreads();
        s[t] += v;
        __syncthreads();
    }
    int run = s[t] - sum;
    for (int i = lo; i < hi; ++i) { rowptr[i] = run; run += cnt[i]; }
    if (t == 1023) rowptr[n] = run;
}

__global__ __launch_bounds__(256) void scatter_kernel(const int* __restrict__ src,
        const int* __restrict__ dst, const float* __restrict__ ea,
        const int* __restrict__ rowptr, int* __restrict__ cursor,
        int* __restrict__ srcS, int* __restrict__ dstS, u16* __restrict__ eaS, int E) {
    int e = blockIdx.x * 256 + threadIdx.x;
    if (e >= E) return;
    int d = dst[e];
    int p = rowptr[d] + atomicAdd(&cursor[d], 1);
    srcS[p] = src[e];
    dstS[p] = d;
    const float* q = &ea[(size_t)e * EDIM];
    ushort4 v;
    v.x = f2bf(q[0]); v.y = f2bf(q[1]); v.z = f2bf(q[2]); v.w = f2bf(q[3]);
    *(ushort4*)&eaS[(size_t)p * 4] = v;
}

// embed + zero agg + graph counts (fused)
__global__ __launch_bounds__(HID) void embed_kernel(const int* __restrict__ z,
        const float* __restrict__ emb, u16* __restrict__ xb,
        float* __restrict__ agg, const int* __restrict__ batch,
        float* __restrict__ counts, int n) {
    int i = blockIdx.x;
    if (i >= n) return;
    int t = threadIdx.x;
    xb[(size_t)i * HID + t] = f2bf(emb[(size_t)z[i] * HID + t]);
    agg[(size_t)i * HID + t] = 0.f;
    if (t == 0) unsafeAtomicAdd(&counts[batch[i]], 1.0f);
}

// ---------------- per-node projections: Ys = x@W1src, Y = x@W1dst (fp32) ----
// R22: BOTH halves of edge GEMM1's node-dependent work hoisted (avg degree
// 16 -> 16x dedup each). One x read feeds both GEMMs. fp32 outputs => pure
// reassociation vs fused edge GEMM, no added quantization.
__global__ __launch_bounds__(256) void ys_kernel(
        const u16* __restrict__ xb, const u16* __restrict__ w1sf,
        const u16* __restrict__ w1bf,
        float* __restrict__ Ys, float* __restrict__ Y, int n) {
    const int t    = threadIdx.x;
    const int i0   = blockIdx.x * 32;
    const int wv   = t >> 6, lane = t & 63;
    const int lrow = lane & 15;
    const int kq   = lane >> 4;
    const int kq8  = kq * 8;

    int iN[2];
    #pragma unroll
    for (int mt = 0; mt < 2; ++mt) {
        int i = i0 + mt * 16 + lrow; if (i >= n) i = n - 1;
        iN[mt] = i;
    }
    f32x4 aS[2][2], aB[2][2];
    #pragma unroll
    for (int mt = 0; mt < 2; ++mt)
        #pragma unroll
        for (int nt = 0; nt < 2; ++nt) {
            aS[mt][nt] = (f32x4){0.f, 0.f, 0.f, 0.f};
            aB[mt][nt] = (f32x4){0.f, 0.f, 0.f, 0.f};
        }

    #pragma unroll
    for (int kt = 0; kt < 4; ++kt) {
        bf16x8 ws0 = *(const bf16x8*)&w1sf[((size_t)(kt * 8 + wv * 2 + 0) * 64 + lane) * 8];
        bf16x8 ws1 = *(const bf16x8*)&w1sf[((size_t)(kt * 8 + wv * 2 + 1) * 64 + lane) * 8];
        bf16x8 wb0 = *(const bf16x8*)&w1bf[((size_t)(kt * 8 + wv * 2 + 0) * 64 + lane) * 8];
        bf16x8 wb1 = *(const bf16x8*)&w1bf[((size_t)(kt * 8 + wv * 2 + 1) * 64 + lane) * 8];
        #pragma unroll
        for (int mt = 0; mt < 2; ++mt) {
            bf16x8 a = as_bf(*(const us8*)&xb[(size_t)iN[mt] * HID + kt * 32 + kq8]);
            aS[mt][0] = __builtin_amdgcn_mfma_f32_16x16x32_bf16(ws0, a, aS[mt][0], 0, 0, 0);
            aS[mt][1] = __builtin_amdgcn_mfma_f32_16x16x32_bf16(ws1, a, aS[mt][1], 0, 0, 0);
            aB[mt][0] = __builtin_amdgcn_mfma_f32_16x16x32_bf16(wb0, a, aB[mt][0], 0, 0, 0);
            aB[mt][1] = __builtin_amdgcn_mfma_f32_16x16x32_bf16(wb1, a, aB[mt][1], 0, 0, 0);
        }
    }
    // swapped-operand layout: lane holds row node=i0+mt*16+lrow,
    // cols (wv*2+nt)*16 + kq*4 .. +3
    #pragma unroll
    for (int mt = 0; mt < 2; ++mt) {
        int node = i0 + mt * 16 + lrow;
        if (node < n) {
            #pragma unroll
            for (int nt = 0; nt < 2; ++nt) {
                *(f32x4*)&Ys[(size_t)node * HID + (wv * 2 + nt) * 16 + kq * 4] = aS[mt][nt];
                *(f32x4*)&Y [(size_t)node * HID + (wv * 2 + nt) * 16 + kq * 4] = aB[mt][nt];
            }
        }
    }
}

// ---------------- edge MLP: 64 dst-sorted edges/block, 8 waves --------------
// R12 core + R15 wave-local scan + R16 (8 waves, swapped MFMA operands) +
// R17 (dst-dedup) + R22 (this round): SRC projection hoisted too. Edge
// GEMM1 is now attr-only (K=32, 1 kt); acc init = b1 + Ys[src] + Y[dst].
// The x-staging loop (128 gathers + 128 ds_writes/block), 4/5 of GEMM1
// MFMAs, and 32KB/block of W1 fragment streaming are DELETED — the three
// ~50%-busy pipes (VALU/DS/VMEM) all shed work. H/GEMM2/M/scan + 4-barrier
// alias scheme byte-identical to R2 (proven 146 us core). LDS 34304 ->
// 4 blocks/CU.
// FAILED variants (do not reintroduce): R9 XOR-swizzle 32KB (235 us),
// R13 2x2 wave tiling (164 us), R16 occupancy 2x (flat; throughput-bound),
// R18 VGPR-persistent weights (spill, 197 us), R19 node-centric full-layer
// fusion (L2 thrash, FETCH 10x, 840 us), R21/R5 fused node tail (node
// 35->470 us, WRITE 174MB, pipes idle — mechanism unresolved), R20/R6
// H-split 2-barrier (occupancy 82->62, edge 146->152).
__global__ __launch_bounds__(512, 8) void edge_mfma(
        const int* __restrict__ srcS, const int* __restrict__ dstS,
        const u16* __restrict__ eaS,
        const u16* __restrict__ w1tf, const float* __restrict__ b1,
        const u16* __restrict__ w2f, const float* __restrict__ b2,
        const float* __restrict__ Ys, const float* __restrict__ Y,
        float* __restrict__ agg, int nE) {
    // A: u16 [64][40] = 5120 B (attr only; dead after GEMM1)
    // H: u16 [64][136] = 17408 B (aliases A; dead after GEMM2)
    // M: f32 [64][132] = 33792 B (aliases A/H; sized to M)
    __shared__ __align__(16) char smem[64 * 132 * 4];
    __shared__ __align__(16) int dsh[64];
    __shared__ __align__(16) int ssh[64];
    u16*   A = (u16*)smem;
    u16*   H = (u16*)smem;
    float* M = (float*)smem;

    const int t    = threadIdx.x;
    const int e0   = blockIdx.x * 64;
    const int wv   = t >> 6, lane = t & 63;
    const int lrow = lane & 15;
    const int kq   = lane >> 4;
    const int kq8  = kq * 8;
    const int rq   = kq * 4;
    const int h    = wv >> 2;     // edge-half this wave owns (0/1)
    const int p    = wv & 3;      // col-pair this wave owns (0..3)

    // ---- stage: dsh/ssh + attr rows (64 x 32 bf16, rows padded to 40) ----
    if (t < 64) {
        int e = e0 + t;
        bool valid = e < nE; if (!valid) e = nE - 1;
        dsh[t] = valid ? dstS[e] : -1;
        ssh[t] = srcS[e];
        ushort4 q = *(const ushort4*)&eaS[(size_t)e * 4];
        int base = t * 40;
        us8 z8 = (us8){0, 0, 0, 0, 0, 0, 0, 0};
        *(us8*)&A[base + 8]  = z8;         // K-pad cols 8..31 zero
        *(us8*)&A[base + 16] = z8;
        *(us8*)&A[base + 24] = z8;
        A[base + 0] = q.x; A[base + 1] = q.y; A[base + 2] = q.z; A[base + 3] = q.w;
        A[base + 4] = 0;   A[base + 5] = 0;   A[base + 6] = 0;   A[base + 7] = 0;
    }
    __syncthreads();

    // ---- GEMM1: attr-only K=32. acc init = b1 + Ys[src] + Y[dst].
    //      Lane (lrow,kq) holds n = (p*2+nt)*16 + rq + r, edge = (h*2+mt)*16+lrow.
    f32x4 acc[2][2];
    #pragma unroll
    for (int mt = 0; mt < 2; ++mt) {
        int edge = (h * 2 + mt) * 16 + lrow;
        int d = dsh[edge]; if (d < 0) d = 0;   // tail-safe (unused result)
        int s = ssh[edge];
        #pragma unroll
        for (int nt = 0; nt < 2; ++nt) {
            f32x4 bv = *(const f32x4*)&b1[(p * 2 + nt) * 16 + rq];
            f32x4 yv = *(const f32x4*)&Y [(size_t)d * HID + (p * 2 + nt) * 16 + rq];
            f32x4 sv = *(const f32x4*)&Ys[(size_t)s * HID + (p * 2 + nt) * 16 + rq];
            acc[mt][nt] = bv + yv + sv;
        }
    }
    {
        bf16x8 w0 = *(const bf16x8*)&w1tf[((size_t)(p * 2 + 0) * 64 + lane) * 8];
        bf16x8 w1 = *(const bf16x8*)&w1tf[((size_t)(p * 2 + 1) * 64 + lane) * 8];
        #pragma unroll
        for (int mt = 0; mt < 2; ++mt) {
            bf16x8 a = *(const bf16x8*)&A[((h * 2 + mt) * 16 + lrow) * 40 + kq8];
            acc[mt][0] = __builtin_amdgcn_mfma_f32_16x16x32_bf16(w0, a, acc[mt][0], 0, 0, 0);
            acc[mt][1] = __builtin_amdgcn_mfma_f32_16x16x32_bf16(w1, a, acc[mt][1], 0, 0, 0);
        }
    }
    __syncthreads();   // all A reads done; region reused as H

    // silu -> H: 4 consecutive n per lane -> one packed b64 per (mt,nt)
    #pragma unroll
    for (int mt = 0; mt < 2; ++mt)
        #pragma unroll
        for (int nt = 0; nt < 2; ++nt) {
            uint2 hv;
            hv.x = pack_bf2(silu_f(acc[mt][nt][0]), silu_f(acc[mt][nt][1]));
            hv.y = pack_bf2(silu_f(acc[mt][nt][2]), silu_f(acc[mt][nt][3]));
            int edge = (h * 2 + mt) * 16 + lrow;
            *(uint2*)&H[edge * 136 + (p * 2 + nt) * 16 + rq] = hv;
        }
    __syncthreads();

    // ---- GEMM2: [64 x 128] @ [128 x 128], swapped operands ----
    f32x4 acc2[2][2];
    #pragma unroll
    for (int nt = 0; nt < 2; ++nt) {
        f32x4 bv = *(const f32x4*)&b2[(p * 2 + nt) * 16 + rq];
        acc2[0][nt] = bv; acc2[1][nt] = bv;
    }
    #pragma unroll
    for (int kt = 0; kt < 4; ++kt) {
        bf16x8 w0 = *(const bf16x8*)&w2f[((size_t)(kt * 8 + p * 2 + 0) * 64 + lane) * 8];
        bf16x8 w1 = *(const bf16x8*)&w2f[((size_t)(kt * 8 + p * 2 + 1) * 64 + lane) * 8];
        #pragma unroll
        for (int mt = 0; mt < 2; ++mt) {
            bf16x8 a = *(const bf16x8*)&H[((h * 2 + mt) * 16 + lrow) * 136 + kt * 32 + kq8];
            acc2[mt][0] = __builtin_amdgcn_mfma_f32_16x16x32_bf16(w0, a, acc2[mt][0], 0, 0, 0);
            acc2[mt][1] = __builtin_amdgcn_mfma_f32_16x16x32_bf16(w1, a, acc2[mt][1], 0, 0, 0);
        }
    }
    __syncthreads();   // all H reads complete before M overwrites (aliased WAR)

    // silu -> M: fp32 messages, one float4 store per (mt,nt)
    #pragma unroll
    for (int mt = 0; mt < 2; ++mt)
        #pragma unroll
        for (int nt = 0; nt < 2; ++nt) {
            f32x4 mv;
            #pragma unroll
            for (int r = 0; r < 4; ++r) mv[r] = silu_f(acc2[mt][nt][r]);
            int edge = (h * 2 + mt) * 16 + lrow;
            *(f32x4*)&M[edge * 132 + (p * 2 + nt) * 16 + rq] = mv;
        }

    // ---- wave-local segmented reduction: wave (h,p) scans exactly the
    // 32-row x 32-col M region it wrote (NO barrier; intra-wave DS program
    // order + compiler lgkmcnt waits guarantee visibility). dsh preloaded
    // as 4x ds_read_b128.
    {
        int col = p * 32 + (lane & 31);
        int r0  = h * 32 + (lane >> 5) * 16;   // rows r0..r0+15
        int4 da = *(const int4*)&dsh[r0];
        int4 db = *(const int4*)&dsh[r0 + 4];
        int4 dc = *(const int4*)&dsh[r0 + 8];
        int4 dd = *(const int4*)&dsh[r0 + 12];
        int ds_[16] = {da.x, da.y, da.z, da.w, db.x, db.y, db.z, db.w,
                       dc.x, dc.y, dc.z, dc.w, dd.x, dd.y, dd.z, dd.w};
        float run = 0.f;
        int   cur = ds_[0];
        #pragma unroll
        for (int i = 0; i < 16; ++i) {
            run += M[(r0 + i) * 132 + col];
            int nxt = (i == 15) ? -2 : ds_[i + 1];
            if (cur != nxt) {             // uniform within 32-lane half
                if (cur >= 0)
                    unsafeAtomicAdd(&agg[(size_t)cur * HID + col], run);
                run = 0.f; cur = nxt;
            }
        }
    }
}

// ---------------- node MLP: 32 nodes/block (R2-exact, proven fast) ----------
// last==0: x = silu([x|agg]@nw+nb) in place, then zero own agg cells.
// last==1: scatter silu(...) directly into per-graph sums (no x store).
__global__ __launch_bounds__(256) void node_mfma(
        u16* __restrict__ xb, float* __restrict__ agg,
        const u16* __restrict__ nwf, const float* __restrict__ nb,
        const int* __restrict__ batch, float* __restrict__ sums,
        int last, int n) {
    const int t    = threadIdx.x;
    const int i0   = blockIdx.x * 32;
    const int wv   = t >> 6, lane = t & 63;
    const int lrow = lane & 15;
    const int kq   = lane >> 4;
    const int kq8  = kq * 8;
    const int rq   = kq * 4;

    int iN[2];
    #pragma unroll
    for (int mt = 0; mt < 2; ++mt) {
        int i = i0 + mt * 16 + lrow; if (i >= n) i = n - 1;
        iN[mt] = i;
    }

    f32x4 acc[2][2];
    {
        float bias0 = nb[wv * 32 + lrow], bias1 = nb[wv * 32 + 16 + lrow];
        #pragma unroll
        for (int mt = 0; mt < 2; ++mt)
            #pragma unroll
            for (int r = 0; r < 4; ++r) {
                acc[mt][0][r] = bias0; acc[mt][1][r] = bias1;
            }
    }
    #pragma unroll
    for (int kt = 0; kt < 4; ++kt) {     // x part (k 0..127)
        bf16x8 w0 = *(const bf16x8*)&nwf[((size_t)(kt * 8 + wv * 2 + 0) * 64 + lane) * 8];
        bf16x8 w1 = *(const bf16x8*)&nwf[((size_t)(kt * 8 + wv * 2 + 1) * 64 + lane) * 8];
        #pragma unroll
        for (int mt = 0; mt < 2; ++mt) {
            bf16x8 a = as_bf(*(const us8*)&xb[(size_t)iN[mt] * HID + kt * 32 + kq8]);
            acc[mt][0] = __builtin_amdgcn_mfma_f32_16x16x32_bf16(a, w0, acc[mt][0], 0, 0, 0);
            acc[mt][1] = __builtin_amdgcn_mfma_f32_16x16x32_bf16(a, w1, acc[mt][1], 0, 0, 0);
        }
    }
    #pragma unroll
    for (int kt = 4; kt < 8; ++kt) {     // agg part (k 128..255), fp32 -> bf16
        bf16x8 w0 = *(const bf16x8*)&nwf[((size_t)(kt * 8 + wv * 2 + 0) * 64 + lane) * 8];
        bf16x8 w1 = *(const bf16x8*)&nwf[((size_t)(kt * 8 + wv * 2 + 1) * 64 + lane) * 8];
        #pragma unroll
        for (int mt = 0; mt < 2; ++mt) {
            const float* pa = &agg[(size_t)iN[mt] * HID + (kt - 4) * 32 + kq8];
            float4 f0 = *(const float4*)pa;
            float4 f1 = *(const float4*)(pa + 4);
            us8 av;
            av[0] = f2bf_fast(f0.x); av[1] = f2bf_fast(f0.y);
            av[2] = f2bf_fast(f0.z); av[3] = f2bf_fast(f0.w);
            av[4] = f2bf_fast(f1.x); av[5] = f2bf_fast(f1.y);
            av[6] = f2bf_fast(f1.z); av[7] = f2bf_fast(f1.w);
            bf16x8 a = as_bf(av);
            acc[mt][0] = __builtin_amdgcn_mfma_f32_16x16x32_bf16(a, w0, acc[mt][0], 0, 0, 0);
            acc[mt][1] = __builtin_amdgcn_mfma_f32_16x16x32_bf16(a, w1, acc[mt][1], 0, 0, 0);
        }
    }

    if (!last) {
        __syncthreads();   // all xb/agg reads in block complete before overwrite
        const float4 z4 = make_float4(0.f, 0.f, 0.f, 0.f);
        #pragma unroll
        for (int kt = 0; kt < 4; ++kt)
            #pragma unroll
            for (int mt = 0; mt < 2; ++mt) {
                float* pa = &agg[(size_t)iN[mt] * HID + kt * 32 + kq8];
                *(float4*)pa = z4; *(float4*)(pa + 4) = z4;
            }
        #pragma unroll
        for (int mt = 0; mt < 2; ++mt)
            #pragma unroll
            for (int nt2 = 0; nt2 < 2; ++nt2)
                #pragma unroll
                for (int r = 0; r < 4; ++r) {
                    int i = i0 + mt * 16 + rq + r;
                    if (i < n)
                        xb[(size_t)i * HID + wv * 32 + nt2 * 16 + lrow] =
                            f2bf_fast(silu_f(acc[mt][nt2][r]));
                }
    } else {
        // final layer: scatter straight into per-graph sums
        #pragma unroll
        for (int mt = 0; mt < 2; ++mt)
            #pragma unroll
            for (int nt2 = 0; nt2 < 2; ++nt2)
                #pragma unroll
                for (int r = 0; r < 4; ++r) {
                    int i = i0 + mt * 16 + rq + r;
                    if (i < n) {
                        int b = batch[i];
                        unsafeAtomicAdd(&sums[(size_t)b * HID + wv * 32 + nt2 * 16 + lrow],
                                        silu_f(acc[mt][nt2][r]));
                    }
                }
    }
}

// ---------------- readout ---------------------------------------------------
__global__ __launch_bounds__(HID) void readout_kernel(
        const float* __restrict__ sums, const float* __restrict__ counts,
        const float* __restrict__ rw1, const float* __restrict__ rb1,
        const float* __restrict__ rw2, const float* __restrict__ rb2,
        float* __restrict__ pred) {
    __shared__ float gv[HID];
    __shared__ float hv[HID];
    const int g = blockIdx.x;
    const int t = threadIdx.x;
    float c = counts[g];
    if (c < 1.0f) c = 1.0f;
    gv[t] = sums[(size_t)g * HID + t] / c;   // cold path: keep exact division
    __syncthreads();
    float acc = rb1[t];
    for (int k4 = 0; k4 < 32; ++k4) {
        float4 mv = *(const float4*)&gv[k4 * 4];
        #pragma unroll
        for (int j = 0; j < 4; ++j)
            acc += ((const float*)&mv)[j] * rw1[(size_t)(k4 * 4 + j) * HID + t];
    }
    hv[t] = silu_f(acc) * rw2[t];
    __syncthreads();
    for (int s = HID / 2; s > 0; s >>= 1) {
        if (t < s) hv[t] += hv[t + s];
        __syncthreads();
    }
    if (t == 0) pred[g] = hv[0] + rb2[0];
}

extern "C" void kernel_launch(void* const* d_in, const int* in_sizes, int n_in,
                              void* d_out, int out_size, void* d_ws, size_t ws_size,
                              hipStream_t stream) {
    const int*   z          = (const int*)d_in[0];
    const int*   edge_index = (const int*)d_in[1];
    const float* edge_attr  = (const float*)d_in[2];
    const int*   batch      = (const int*)d_in[3];
    const float* emb        = (const float*)d_in[4];
    const float* ew1        = (const float*)d_in[5];
    const float* eb1        = (const float*)d_in[6];
    const float* ew2        = (const float*)d_in[7];
    const float* eb2        = (const float*)d_in[8];
    const float* nw         = (const float*)d_in[9];
    const float* nb         = (const float*)d_in[10];
    const float* rw1        = (const float*)d_in[11];
    const float* rb1        = (const float*)d_in[12];
    const float* rw2        = (const float*)d_in[13];
    const float* rb2        = (const float*)d_in[14];
    float* pred = (float*)d_out;

    const int N = in_sizes[0];
    const int E = in_sizes[1] / 2;
    const int G = out_size;
    const int* srcI = edge_index;
    const int* dstI = edge_index + E;

    char* base = (char*)d_ws;
    size_t off = 0;
    auto carve = [&](size_t bytes) -> char* {
        char* p = base + off;
        off = (off + bytes + 255) & ~(size_t)255;
        return p;
    };
    float* agg    = (float*)carve((size_t)N * HID * sizeof(float));
    float* sums   = (float*)carve((size_t)G * HID * sizeof(float));
    float* cnts_g = (float*)carve((size_t)G * sizeof(float));
    u16*   xb     = (u16*)carve((size_t)N * HID * sizeof(u16));
    float* Y      = (float*)carve((size_t)N * HID * sizeof(float));  // dst-proj
    float* Ys     = (float*)carve((size_t)N * HID * sizeof(float));  // src-proj
    int*   srcS   = (int*)carve((size_t)(E + 64) * sizeof(int));
    int*   dstS   = (int*)carve((size_t)(E + 64) * sizeof(int));
    u16*   eaS    = (u16*)carve((size_t)(E + 64) * 4 * sizeof(u16));
    int*   rowptr = (int*)carve((size_t)(N + 1) * sizeof(int));
    int*   cursor = (int*)carve((size_t)N * sizeof(int));
    int*   cnt    = (int*)carve((size_t)N * sizeof(int));
    u16*   w1sf   = (u16*)carve((size_t)4 * 32 * 512 * sizeof(u16)); // KT=4 src
    u16*   w1tf   = (u16*)carve((size_t)4 * 8 * 512 * sizeof(u16));  // KT=1 attr
    u16*   w1bf   = (u16*)carve((size_t)4 * 32 * 512 * sizeof(u16)); // KT=4 dst
    u16*   w2f    = (u16*)carve((size_t)4 * 32 * 512 * sizeof(u16)); // KT=4
    u16*   nwf    = (u16*)carve((size_t)4 * 64 * 512 * sizeof(u16)); // KT=8

    // ---- fused setup: weight swizzle + zero cnt/cursor/sums/counts ----
    {
        long long total = (long long)T1S + T1T + T1B + T2 + T3
                        + 2LL * N + (long long)G * HID + G;
        int blocks = (int)((total + 255) / 256);
        setup_kernel<<<blocks, 256, 0, stream>>>(ew1, ew2, nw, w1sf, w1tf, w1bf,
                                                 w2f, nwf, cnt, cursor,
                                                 sums, cnts_g, N, G);
    }

    // ---- CSR build (dst-sorted edges) ----
    hist_kernel<<<(E + 255) / 256, 256, 0, stream>>>(dstI, cnt, E);
    scan_kernel<<<1, 1024, 0, stream>>>(cnt, rowptr, N);
    scatter_kernel<<<(E + 255) / 256, 256, 0, stream>>>(
        srcI, dstI, edge_attr, rowptr, cursor, srcS, dstS, eaS, E);

    // embed + zero agg + graph counts
    embed_kernel<<<N, HID, 0, stream>>>(z, emb, xb, agg, batch, cnts_g, N);

    for (int l = 0; l < 4; ++l) {
        ys_kernel<<<(N + 31) / 32, 256, 0, stream>>>(
            xb, w1sf + (size_t)l * 32 * 512, w1bf + (size_t)l * 32 * 512,
            Ys, Y, N);
        edge_mfma<<<(E + 63) / 64, 512, 0, stream>>>(
            srcS, dstS, eaS,
            w1tf + (size_t)l * 8 * 512, eb1 + (size_t)l * HID,
            w2f + (size_t)l * 32 * 512, eb2 + (size_t)l * HID,
            Ys, Y, agg, E);
        node_mfma<<<(N + 31) / 32, 256, 0, stream>>>(
            xb, agg, nwf + (size_t)l * 64 * 512, nb + (size_t)l * HID,
            batch, sums, (l == 3) ? 1 : 0, N);
    }

    readout_kernel<<<G, HID, 0, stream>>>(sums, cnts_g, rw1, rb1, rw2, rb2, pred);
}

// Round 8
// 1074.630 us; speedup vs baseline: 2.1678x; 1.0464x over previous
//
#include <hip/hip_runtime.h>
#include <math.h>

#define HID  128
#define EDIM 4

typedef unsigned short u16;
typedef u16    us8   __attribute__((ext_vector_type(8)));
typedef __bf16 bf16x8 __attribute__((ext_vector_type(8)));
typedef float  f32x4 __attribute__((ext_vector_type(4)));

// silu via hw rcp: v_rcp_f32 (~1 ulp) instead of IEEE div (10+ inst w/o fast-math)
__device__ __forceinline__ float silu_f(float v) {
    return v * __builtin_amdgcn_rcpf(1.0f + __expf(-v));
}
__device__ __forceinline__ u16 f2bf(float f) {   // RNE fp32->bf16 (cold paths)
    unsigned u = __float_as_uint(f);
    unsigned r = u + 0x7fffu + ((u >> 16) & 1u);
    return (u16)(r >> 16);
}
__device__ __forceinline__ u16 f2bf_fast(float f) {  // round-half-up, 2 ops (hot)
    return (u16)((__float_as_uint(f) + 0x8000u) >> 16);
}
// pack two fp32 -> one u32 of 2 bf16 (round-half-up)
__device__ __forceinline__ unsigned pack_bf2(float a, float b) {
    return ((__float_as_uint(a) + 0x8000u) >> 16) |
           ((__float_as_uint(b) + 0x8000u) & 0xffff0000u);
}
__device__ __forceinline__ float bf2f(u16 s) {
    return __uint_as_float(((unsigned)s) << 16);
}
__device__ __forceinline__ bf16x8 as_bf(us8 v) {
    return __builtin_bit_cast(bf16x8, v);
}

// ---------------- fused setup: weight swizzle + zero-fills ------------------
// Generalized fragment swizzler: logical k -> source row = k + (k>=split ?
// jump : 0); valid iff row < Kdata. Layer stride Kstride rows.
__device__ __forceinline__ void wfrag_gen(const float* __restrict__ w,
        u16* __restrict__ out, int KT, int Kdata, int Kstride,
        int split, int jump, int idx) {
    int lane = idx & 63;
    int f    = (idx >> 6) % (KT * 8);
    int l    = idx / (64 * KT * 8);
    int kt = f >> 3, nt = f & 7;
    int n  = nt * 16 + (lane & 15);
    int k0 = kt * 32 + ((lane >> 4) * 8);
    us8 v;
    #pragma unroll
    for (int j = 0; j < 8; ++j) {
        int k = k0 + j;
        int row = k + (k >= split ? jump : 0);
        v[j] = (row < Kdata) ? f2bf(w[((size_t)l * Kstride + row) * HID + n]) : (u16)0;
    }
    *(us8*)&out[((size_t)(l * KT * 8 + f) * 64 + lane) * 8] = v;
}

// R22 split of W1 [260x128]: w1s (src rows 0..127, KT=4), w1b (dst rows
// 128..255, KT=4), w1t (attr rows 256..259 zero-padded to K=32, KT=1).
#define T1S (4 * 4 * 8 * 64)
#define T1T (4 * 1 * 8 * 64)
#define T1B (4 * 4 * 8 * 64)
#define T2  (4 * 4 * 8 * 64)
#define T3  (4 * 8 * 8 * 64)

__global__ __launch_bounds__(256) void setup_kernel(
        const float* __restrict__ ew1, const float* __restrict__ ew2,
        const float* __restrict__ nw,
        u16* __restrict__ w1sf, u16* __restrict__ w1tf,
        u16* __restrict__ w1bf,
        u16* __restrict__ w2f, u16* __restrict__ nwf,
        int* __restrict__ cnt, int* __restrict__ cursor,
        float* __restrict__ sums, float* __restrict__ cnts_g, int N, int G) {
    const int BIG = 1 << 30;
    int idx = blockIdx.x * 256 + threadIdx.x;
    if (idx < T1S) { wfrag_gen(ew1, w1sf, 4, 128, 260, BIG, 0, idx); return; }
    idx -= T1S;
    if (idx < T1T) { wfrag_gen(ew1, w1tf, 1, 260, 260, 0, 256, idx); return; }
    idx -= T1T;
    if (idx < T1B) { wfrag_gen(ew1, w1bf, 4, 260, 260, 0, 128, idx); return; }
    idx -= T1B;
    if (idx < T2) { wfrag_gen(ew2, w2f, 4, 128, 128, BIG, 0, idx); return; }
    idx -= T2;
    if (idx < T3) { wfrag_gen(nw, nwf, 8, 256, 256, BIG, 0, idx); return; }
    idx -= T3;
    if (idx < N) { cnt[idx] = 0; return; }
    idx -= N;
    if (idx < N) { cursor[idx] = 0; return; }
    idx -= N;
    if (idx < G * HID) { sums[idx] = 0.f; return; }
    idx -= G * HID;
    if (idx < G) { cnts_g[idx] = 0.f; return; }
}

// ---------------- CSR build: hist -> scan -> scatter ------------------------
__global__ __launch_bounds__(256) void hist_kernel(const int* __restrict__ dst,
        int* __restrict__ cnt, int E) {
    int e = blockIdx.x * 256 + threadIdx.x;
    if (e < E) atomicAdd(&cnt[dst[e]], 1);
}

__global__ __launch_bounds__(1024) void scan_kernel(const int* __restrict__ cnt,
        int* __restrict__ rowptr, int n) {
    __shared__ int s[1024];
    const int t = threadIdx.x;
    const int chunk = (n + 1023) >> 10;
    int lo = t * chunk, hi = lo + chunk;
    if (lo > n) lo = n;
    if (hi > n) hi = n;
    int sum = 0;
    for (int i = lo; i < hi; ++i) sum += cnt[i];
    s[t] = sum;
    __syncthreads();
    for (int off = 1; off < 1024; off <<= 1) {
        int v = (t >= off) ? s[t - off] : 0;
        __syncthreads();
        s[t] += v;
        __syncthreads();
    }
    int run = s[t] - sum;
    for (int i = lo; i < hi; ++i) { rowptr[i] = run; run += cnt[i]; }
    if (t == 1023) rowptr[n] = run;
}

__global__ __launch_bounds__(256) void scatter_kernel(const int* __restrict__ src,
        const int* __restrict__ dst, const float* __restrict__ ea,
        const int* __restrict__ rowptr, int* __restrict__ cursor,
        int* __restrict__ srcS, int* __restrict__ dstS, u16* __restrict__ eaS, int E) {
    int e = blockIdx.x * 256 + threadIdx.x;
    if (e >= E) return;
    int d = dst[e];
    int p = rowptr[d] + atomicAdd(&cursor[d], 1);
    srcS[p] = src[e];
    dstS[p] = d;
    const float* q = &ea[(size_t)e * EDIM];
    ushort4 v;
    v.x = f2bf(q[0]); v.y = f2bf(q[1]); v.z = f2bf(q[2]); v.w = f2bf(q[3]);
    *(ushort4*)&eaS[(size_t)p * 4] = v;
}

// ---------------- shared dual-projection tail (bit-identical to R7's
// ys_kernel body): Ys = x@W1s, Y = x@W1b from the block's own 32 xb rows.
// Caller must __syncthreads() after writing those rows (vmcnt drain at the
// barrier makes them block-visible via L2).
__device__ __forceinline__ void dual_proj(
        const u16* __restrict__ xb,
        const u16* __restrict__ w1sf, const u16* __restrict__ w1bf,
        float* __restrict__ Ys, float* __restrict__ Y,
        int i0, int n, int t) {
    const int wv   = t >> 6, lane = t & 63;
    const int lrow = lane & 15;
    const int kq   = lane >> 4;
    const int kq8  = kq * 8;

    int iN[2];
    #pragma unroll
    for (int mt = 0; mt < 2; ++mt) {
        int i = i0 + mt * 16 + lrow; if (i >= n) i = n - 1;
        iN[mt] = i;
    }
    f32x4 aS[2][2], aB[2][2];
    #pragma unroll
    for (int mt = 0; mt < 2; ++mt)
        #pragma unroll
        for (int nt = 0; nt < 2; ++nt) {
            aS[mt][nt] = (f32x4){0.f, 0.f, 0.f, 0.f};
            aB[mt][nt] = (f32x4){0.f, 0.f, 0.f, 0.f};
        }

    #pragma unroll
    for (int kt = 0; kt < 4; ++kt) {
        bf16x8 ws0 = *(const bf16x8*)&w1sf[((size_t)(kt * 8 + wv * 2 + 0) * 64 + lane) * 8];
        bf16x8 ws1 = *(const bf16x8*)&w1sf[((size_t)(kt * 8 + wv * 2 + 1) * 64 + lane) * 8];
        bf16x8 wb0 = *(const bf16x8*)&w1bf[((size_t)(kt * 8 + wv * 2 + 0) * 64 + lane) * 8];
        bf16x8 wb1 = *(const bf16x8*)&w1bf[((size_t)(kt * 8 + wv * 2 + 1) * 64 + lane) * 8];
        #pragma unroll
        for (int mt = 0; mt < 2; ++mt) {
            bf16x8 a = as_bf(*(const us8*)&xb[(size_t)iN[mt] * HID + kt * 32 + kq8]);
            aS[mt][0] = __builtin_amdgcn_mfma_f32_16x16x32_bf16(ws0, a, aS[mt][0], 0, 0, 0);
            aS[mt][1] = __builtin_amdgcn_mfma_f32_16x16x32_bf16(ws1, a, aS[mt][1], 0, 0, 0);
            aB[mt][0] = __builtin_amdgcn_mfma_f32_16x16x32_bf16(wb0, a, aB[mt][0], 0, 0, 0);
            aB[mt][1] = __builtin_amdgcn_mfma_f32_16x16x32_bf16(wb1, a, aB[mt][1], 0, 0, 0);
        }
    }
    // swapped-operand layout: lane holds row node=i0+mt*16+lrow,
    // cols (wv*2+nt)*16 + kq*4 .. +3
    #pragma unroll
    for (int mt = 0; mt < 2; ++mt) {
        int node = i0 + mt * 16 + lrow;
        if (node < n) {
            #pragma unroll
            for (int nt = 0; nt < 2; ++nt) {
                *(f32x4*)&Ys[(size_t)node * HID + (wv * 2 + nt) * 16 + kq * 4] = aS[mt][nt];
                *(f32x4*)&Y [(size_t)node * HID + (wv * 2 + nt) * 16 + kq * 4] = aB[mt][nt];
            }
        }
    }
}

// ---------------- embed + zero agg + counts + layer-0 projections -----------
// R23: 32 nodes/block. Embeds x, zeroes agg, bumps graph counts, then (after
// barrier-drain) computes layer-0 Ys/Y from the freshly written xb rows —
// replaces the standalone ys_kernel launch for l=0.
__global__ __launch_bounds__(256) void embed_ys_kernel(
        const int* __restrict__ z, const float* __restrict__ emb,
        u16* __restrict__ xb, float* __restrict__ agg,
        const int* __restrict__ batch, float* __restrict__ counts,
        const u16* __restrict__ w1sf, const u16* __restrict__ w1bf,
        float* __restrict__ Ys, float* __restrict__ Y, int n) {
    const int t  = threadIdx.x;
    const int i0 = blockIdx.x * 32;
    #pragma unroll
    for (int j = 0; j < 16; ++j) {
        int idx = j * 256 + t;                 // 4096 slots = 32 nodes x 128
        int node = i0 + (idx >> 7), col = idx & 127;
        if (node < n) {
            xb[(size_t)node * HID + col] = f2bf(emb[(size_t)z[node] * HID + col]);
            agg[(size_t)node * HID + col] = 0.f;
        }
    }
    if (t < 32 && i0 + t < n)
        unsafeAtomicAdd(&counts[batch[i0 + t]], 1.0f);
    __syncthreads();   // xb stores drained -> L2-visible block-wide
    dual_proj(xb, w1sf, w1bf, Ys, Y, i0, n, t);
}

// ---------------- edge MLP: 64 dst-sorted edges/block, 8 waves --------------
// R12 core + R15 wave-local scan + R16 (8 waves, swapped MFMA operands) +
// R17 (dst-dedup) + R22 (src-hoist: GEMM1 attr-only K=32; acc init =
// b1 + Ys[src] + Y[dst]). BYTE-IDENTICAL to R7 (135 us measured).
// FAILED variants (do not reintroduce): R9 XOR-swizzle 32KB (235 us),
// R13 2x2 wave tiling (164 us), R16 occupancy 2x (flat; throughput-bound),
// R18 VGPR-persistent weights (spill, 197 us), R19 node-centric full-layer
// fusion (L2 thrash, FETCH 10x, 840 us), R21/R5 fused node tail via LDS
// transpose (node 35->470 us, WRITE 174MB, pipes idle — mechanism
// unresolved; R23 retries fusion WITHOUT the LDS path), R20/R6 H-split
// 2-barrier (occupancy 82->62, edge 146->152).
__global__ __launch_bounds__(512, 8) void edge_mfma(
        const int* __restrict__ srcS, const int* __restrict__ dstS,
        const u16* __restrict__ eaS,
        const u16* __restrict__ w1tf, const float* __restrict__ b1,
        const u16* __restrict__ w2f, const float* __restrict__ b2,
        const float* __restrict__ Ys, const float* __restrict__ Y,
        float* __restrict__ agg, int nE) {
    // A: u16 [64][40] = 5120 B (attr only; dead after GEMM1)
    // H: u16 [64][136] = 17408 B (aliases A; dead after GEMM2)
    // M: f32 [64][132] = 33792 B (aliases A/H; sized to M)
    __shared__ __align__(16) char smem[64 * 132 * 4];
    __shared__ __align__(16) int dsh[64];
    __shared__ __align__(16) int ssh[64];
    u16*   A = (u16*)smem;
    u16*   H = (u16*)smem;
    float* M = (float*)smem;

    const int t    = threadIdx.x;
    const int e0   = blockIdx.x * 64;
    const int wv   = t >> 6, lane = t & 63;
    const int lrow = lane & 15;
    const int kq   = lane >> 4;
    const int kq8  = kq * 8;
    const int rq   = kq * 4;
    const int h    = wv >> 2;     // edge-half this wave owns (0/1)
    const int p    = wv & 3;      // col-pair this wave owns (0..3)

    // ---- stage: dsh/ssh + attr rows (64 x 32 bf16, rows padded to 40) ----
    if (t < 64) {
        int e = e0 + t;
        bool valid = e < nE; if (!valid) e = nE - 1;
        dsh[t] = valid ? dstS[e] : -1;
        ssh[t] = srcS[e];
        ushort4 q = *(const ushort4*)&eaS[(size_t)e * 4];
        int base = t * 40;
        us8 z8 = (us8){0, 0, 0, 0, 0, 0, 0, 0};
        *(us8*)&A[base + 8]  = z8;         // K-pad cols 8..31 zero
        *(us8*)&A[base + 16] = z8;
        *(us8*)&A[base + 24] = z8;
        A[base + 0] = q.x; A[base + 1] = q.y; A[base + 2] = q.z; A[base + 3] = q.w;
        A[base + 4] = 0;   A[base + 5] = 0;   A[base + 6] = 0;   A[base + 7] = 0;
    }
    __syncthreads();

    // ---- GEMM1: attr-only K=32. acc init = b1 + Ys[src] + Y[dst].
    //      Lane (lrow,kq) holds n = (p*2+nt)*16 + rq + r, edge = (h*2+mt)*16+lrow.
    f32x4 acc[2][2];
    #pragma unroll
    for (int mt = 0; mt < 2; ++mt) {
        int edge = (h * 2 + mt) * 16 + lrow;
        int d = dsh[edge]; if (d < 0) d = 0;   // tail-safe (unused result)
        int s = ssh[edge];
        #pragma unroll
        for (int nt = 0; nt < 2; ++nt) {
            f32x4 bv = *(const f32x4*)&b1[(p * 2 + nt) * 16 + rq];
            f32x4 yv = *(const f32x4*)&Y [(size_t)d * HID + (p * 2 + nt) * 16 + rq];
            f32x4 sv = *(const f32x4*)&Ys[(size_t)s * HID + (p * 2 + nt) * 16 + rq];
            acc[mt][nt] = bv + yv + sv;
        }
    }
    {
        bf16x8 w0 = *(const bf16x8*)&w1tf[((size_t)(p * 2 + 0) * 64 + lane) * 8];
        bf16x8 w1 = *(const bf16x8*)&w1tf[((size_t)(p * 2 + 1) * 64 + lane) * 8];
        #pragma unroll
        for (int mt = 0; mt < 2; ++mt) {
            bf16x8 a = *(const bf16x8*)&A[((h * 2 + mt) * 16 + lrow) * 40 + kq8];
            acc[mt][0] = __builtin_amdgcn_mfma_f32_16x16x32_bf16(w0, a, acc[mt][0], 0, 0, 0);
            acc[mt][1] = __builtin_amdgcn_mfma_f32_16x16x32_bf16(w1, a, acc[mt][1], 0, 0, 0);
        }
    }
    __syncthreads();   // all A reads done; region reused as H

    // silu -> H: 4 consecutive n per lane -> one packed b64 per (mt,nt)
    #pragma unroll
    for (int mt = 0; mt < 2; ++mt)
        #pragma unroll
        for (int nt = 0; nt < 2; ++nt) {
            uint2 hv;
            hv.x = pack_bf2(silu_f(acc[mt][nt][0]), silu_f(acc[mt][nt][1]));
            hv.y = pack_bf2(silu_f(acc[mt][nt][2]), silu_f(acc[mt][nt][3]));
            int edge = (h * 2 + mt) * 16 + lrow;
            *(uint2*)&H[edge * 136 + (p * 2 + nt) * 16 + rq] = hv;
        }
    __syncthreads();

    // ---- GEMM2: [64 x 128] @ [128 x 128], swapped operands ----
    f32x4 acc2[2][2];
    #pragma unroll
    for (int nt = 0; nt < 2; ++nt) {
        f32x4 bv = *(const f32x4*)&b2[(p * 2 + nt) * 16 + rq];
        acc2[0][nt] = bv; acc2[1][nt] = bv;
    }
    #pragma unroll
    for (int kt = 0; kt < 4; ++kt) {
        bf16x8 w0 = *(const bf16x8*)&w2f[((size_t)(kt * 8 + p * 2 + 0) * 64 + lane) * 8];
        bf16x8 w1 = *(const bf16x8*)&w2f[((size_t)(kt * 8 + p * 2 + 1) * 64 + lane) * 8];
        #pragma unroll
        for (int mt = 0; mt < 2; ++mt) {
            bf16x8 a = *(const bf16x8*)&H[((h * 2 + mt) * 16 + lrow) * 136 + kt * 32 + kq8];
            acc2[mt][0] = __builtin_amdgcn_mfma_f32_16x16x32_bf16(w0, a, acc2[mt][0], 0, 0, 0);
            acc2[mt][1] = __builtin_amdgcn_mfma_f32_16x16x32_bf16(w1, a, acc2[mt][1], 0, 0, 0);
        }
    }
    __syncthreads();   // all H reads complete before M overwrites (aliased WAR)

    // silu -> M: fp32 messages, one float4 store per (mt,nt)
    #pragma unroll
    for (int mt = 0; mt < 2; ++mt)
        #pragma unroll
        for (int nt = 0; nt < 2; ++nt) {
            f32x4 mv;
            #pragma unroll
            for (int r = 0; r < 4; ++r) mv[r] = silu_f(acc2[mt][nt][r]);
            int edge = (h * 2 + mt) * 16 + lrow;
            *(f32x4*)&M[edge * 132 + (p * 2 + nt) * 16 + rq] = mv;
        }

    // ---- wave-local segmented reduction: wave (h,p) scans exactly the
    // 32-row x 32-col M region it wrote (NO barrier; intra-wave DS program
    // order + compiler lgkmcnt waits guarantee visibility). dsh preloaded
    // as 4x ds_read_b128.
    {
        int col = p * 32 + (lane & 31);
        int r0  = h * 32 + (lane >> 5) * 16;   // rows r0..r0+15
        int4 da = *(const int4*)&dsh[r0];
        int4 db = *(const int4*)&dsh[r0 + 4];
        int4 dc = *(const int4*)&dsh[r0 + 8];
        int4 dd = *(const int4*)&dsh[r0 + 12];
        int ds_[16] = {da.x, da.y, da.z, da.w, db.x, db.y, db.z, db.w,
                       dc.x, dc.y, dc.z, dc.w, dd.x, dd.y, dd.z, dd.w};
        float run = 0.f;
        int   cur = ds_[0];
        #pragma unroll
        for (int i = 0; i < 16; ++i) {
            run += M[(r0 + i) * 132 + col];
            int nxt = (i == 15) ? -2 : ds_[i + 1];
            if (cur != nxt) {             // uniform within 32-lane half
                if (cur >= 0)
                    unsafeAtomicAdd(&agg[(size_t)cur * HID + col], run);
                run = 0.f; cur = nxt;
            }
        }
    }
}

// ---------------- node MLP: 32 nodes/block + fused next-layer projections ---
// R2-exact core (non-swapped mfma, scalar xb stores). R23 tail (last==0
// only): after the xb stores + a barrier (vmcnt drain -> L2 visibility),
// run dual_proj on the block's own 32 freshly-written xb rows — the literal
// ys_kernel body, same grid geometry, bit-identical Ys/Y. This is NOT the
// R5 LDS-transpose path (that one regressed 35->470 us; still banned).
__global__ __launch_bounds__(256) void node_mfma(
        u16* __restrict__ xb, float* __restrict__ agg,
        const u16* __restrict__ nwf, const float* __restrict__ nb,
        const int* __restrict__ batch, float* __restrict__ sums,
        const u16* __restrict__ w1sf_nxt, const u16* __restrict__ w1bf_nxt,
        float* __restrict__ Ys, float* __restrict__ Y,
        int last, int n) {
    const int t    = threadIdx.x;
    const int i0   = blockIdx.x * 32;
    const int wv   = t >> 6, lane = t & 63;
    const int lrow = lane & 15;
    const int kq   = lane >> 4;
    const int kq8  = kq * 8;
    const int rq   = kq * 4;

    int iN[2];
    #pragma unroll
    for (int mt = 0; mt < 2; ++mt) {
        int i = i0 + mt * 16 + lrow; if (i >= n) i = n - 1;
        iN[mt] = i;
    }

    f32x4 acc[2][2];
    {
        float bias0 = nb[wv * 32 + lrow], bias1 = nb[wv * 32 + 16 + lrow];
        #pragma unroll
        for (int mt = 0; mt < 2; ++mt)
            #pragma unroll
            for (int r = 0; r < 4; ++r) {
                acc[mt][0][r] = bias0; acc[mt][1][r] = bias1;
            }
    }
    #pragma unroll
    for (int kt = 0; kt < 4; ++kt) {     // x part (k 0..127)
        bf16x8 w0 = *(const bf16x8*)&nwf[((size_t)(kt * 8 + wv * 2 + 0) * 64 + lane) * 8];
        bf16x8 w1 = *(const bf16x8*)&nwf[((size_t)(kt * 8 + wv * 2 + 1) * 64 + lane) * 8];
        #pragma unroll
        for (int mt = 0; mt < 2; ++mt) {
            bf16x8 a = as_bf(*(const us8*)&xb[(size_t)iN[mt] * HID + kt * 32 + kq8]);
            acc[mt][0] = __builtin_amdgcn_mfma_f32_16x16x32_bf16(a, w0, acc[mt][0], 0, 0, 0);
            acc[mt][1] = __builtin_amdgcn_mfma_f32_16x16x32_bf16(a, w1, acc[mt][1], 0, 0, 0);
        }
    }
    #pragma unroll
    for (int kt = 4; kt < 8; ++kt) {     // agg part (k 128..255), fp32 -> bf16
        bf16x8 w0 = *(const bf16x8*)&nwf[((size_t)(kt * 8 + wv * 2 + 0) * 64 + lane) * 8];
        bf16x8 w1 = *(const bf16x8*)&nwf[((size_t)(kt * 8 + wv * 2 + 1) * 64 + lane) * 8];
        #pragma unroll
        for (int mt = 0; mt < 2; ++mt) {
            const float* pa = &agg[(size_t)iN[mt] * HID + (kt - 4) * 32 + kq8];
            float4 f0 = *(const float4*)pa;
            float4 f1 = *(const float4*)(pa + 4);
            us8 av;
            av[0] = f2bf_fast(f0.x); av[1] = f2bf_fast(f0.y);
            av[2] = f2bf_fast(f0.z); av[3] = f2bf_fast(f0.w);
            av[4] = f2bf_fast(f1.x); av[5] = f2bf_fast(f1.y);
            av[6] = f2bf_fast(f1.z); av[7] = f2bf_fast(f1.w);
            bf16x8 a = as_bf(av);
            acc[mt][0] = __builtin_amdgcn_mfma_f32_16x16x32_bf16(a, w0, acc[mt][0], 0, 0, 0);
            acc[mt][1] = __builtin_amdgcn_mfma_f32_16x16x32_bf16(a, w1, acc[mt][1], 0, 0, 0);
        }
    }

    if (!last) {
        __syncthreads();   // all xb/agg reads in block complete before overwrite
        const float4 z4 = make_float4(0.f, 0.f, 0.f, 0.f);
        #pragma unroll
        for (int kt = 0; kt < 4; ++kt)
            #pragma unroll
            for (int mt = 0; mt < 2; ++mt) {
                float* pa = &agg[(size_t)iN[mt] * HID + kt * 32 + kq8];
                *(float4*)pa = z4; *(float4*)(pa + 4) = z4;
            }
        #pragma unroll
        for (int mt = 0; mt < 2; ++mt)
            #pragma unroll
            for (int nt2 = 0; nt2 < 2; ++nt2)
                #pragma unroll
                for (int r = 0; r < 4; ++r) {
                    int i = i0 + mt * 16 + rq + r;
                    if (i < n)
                        xb[(size_t)i * HID + wv * 32 + nt2 * 16 + lrow] =
                            f2bf_fast(silu_f(acc[mt][nt2][r]));
                }
        __syncthreads();   // xb stores drained (vmcnt0 at barrier) -> visible
        dual_proj(xb, w1sf_nxt, w1bf_nxt, Ys, Y, i0, n, t);
    } else {
        // final layer: scatter straight into per-graph sums
        #pragma unroll
        for (int mt = 0; mt < 2; ++mt)
            #pragma unroll
            for (int nt2 = 0; nt2 < 2; ++nt2)
                #pragma unroll
                for (int r = 0; r < 4; ++r) {
                    int i = i0 + mt * 16 + rq + r;
                    if (i < n) {
                        int b = batch[i];
                        unsafeAtomicAdd(&sums[(size_t)b * HID + wv * 32 + nt2 * 16 + lrow],
                                        silu_f(acc[mt][nt2][r]));
                    }
                }
    }
}

// ---------------- readout ---------------------------------------------------
__global__ __launch_bounds__(HID) void readout_kernel(
        const float* __restrict__ sums, const float* __restrict__ counts,
        const float* __restrict__ rw1, const float* __restrict__ rb1,
        const float* __restrict__ rw2, const float* __restrict__ rb2,
        float* __restrict__ pred) {
    __shared__ float gv[HID];
    __shared__ float hv[HID];
    const int g = blockIdx.x;
    const int t = threadIdx.x;
    float c = counts[g];
    if (c < 1.0f) c = 1.0f;
    gv[t] = sums[(size_t)g * HID + t] / c;   // cold path: keep exact division
    __syncthreads();
    float acc = rb1[t];
    for (int k4 = 0; k4 < 32; ++k4) {
        float4 mv = *(const float4*)&gv[k4 * 4];
        #pragma unroll
        for (int j = 0; j < 4; ++j)
            acc += ((const float*)&mv)[j] * rw1[(size_t)(k4 * 4 + j) * HID + t];
    }
    hv[t] = silu_f(acc) * rw2[t];
    __syncthreads();
    for (int s = HID / 2; s > 0; s >>= 1) {
        if (t < s) hv[t] += hv[t + s];
        __syncthreads();
    }
    if (t == 0) pred[g] = hv[0] + rb2[0];
}

extern "C" void kernel_launch(void* const* d_in, const int* in_sizes, int n_in,
                              void* d_out, int out_size, void* d_ws, size_t ws_size,
                              hipStream_t stream) {
    const int*   z          = (const int*)d_in[0];
    const int*   edge_index = (const int*)d_in[1];
    const float* edge_attr  = (const float*)d_in[2];
    const int*   batch      = (const int*)d_in[3];
    const float* emb        = (const float*)d_in[4];
    const float* ew1        = (const float*)d_in[5];
    const float* eb1        = (const float*)d_in[6];
    const float* ew2        = (const float*)d_in[7];
    const float* eb2        = (const float*)d_in[8];
    const float* nw         = (const float*)d_in[9];
    const float* nb         = (const float*)d_in[10];
    const float* rw1        = (const float*)d_in[11];
    const float* rb1        = (const float*)d_in[12];
    const float* rw2        = (const float*)d_in[13];
    const float* rb2        = (const float*)d_in[14];
    float* pred = (float*)d_out;

    const int N = in_sizes[0];
    const int E = in_sizes[1] / 2;
    const int G = out_size;
    const int* srcI = edge_index;
    const int* dstI = edge_index + E;

    char* base = (char*)d_ws;
    size_t off = 0;
    auto carve = [&](size_t bytes) -> char* {
        char* p = base + off;
        off = (off + bytes + 255) & ~(size_t)255;
        return p;
    };
    float* agg    = (float*)carve((size_t)N * HID * sizeof(float));
    float* sums   = (float*)carve((size_t)G * HID * sizeof(float));
    float* cnts_g = (float*)carve((size_t)G * sizeof(float));
    u16*   xb     = (u16*)carve((size_t)N * HID * sizeof(u16));
    float* Y      = (float*)carve((size_t)N * HID * sizeof(float));  // dst-proj
    float* Ys     = (float*)carve((size_t)N * HID * sizeof(float));  // src-proj
    int*   srcS   = (int*)carve((size_t)(E + 64) * sizeof(int));
    int*   dstS   = (int*)carve((size_t)(E + 64) * sizeof(int));
    u16*   eaS    = (u16*)carve((size_t)(E + 64) * 4 * sizeof(u16));
    int*   rowptr = (int*)carve((size_t)(N + 1) * sizeof(int));
    int*   cursor = (int*)carve((size_t)N * sizeof(int));
    int*   cnt    = (int*)carve((size_t)N * sizeof(int));
    u16*   w1sf   = (u16*)carve((size_t)4 * 32 * 512 * sizeof(u16)); // KT=4 src
    u16*   w1tf   = (u16*)carve((size_t)4 * 8 * 512 * sizeof(u16));  // KT=1 attr
    u16*   w1bf   = (u16*)carve((size_t)4 * 32 * 512 * sizeof(u16)); // KT=4 dst
    u16*   w2f    = (u16*)carve((size_t)4 * 32 * 512 * sizeof(u16)); // KT=4
    u16*   nwf    = (u16*)carve((size_t)4 * 64 * 512 * sizeof(u16)); // KT=8

    // ---- fused setup: weight swizzle + zero cnt/cursor/sums/counts ----
    {
        long long total = (long long)T1S + T1T + T1B + T2 + T3
                        + 2LL * N + (long long)G * HID + G;
        int blocks = (int)((total + 255) / 256);
        setup_kernel<<<blocks, 256, 0, stream>>>(ew1, ew2, nw, w1sf, w1tf, w1bf,
                                                 w2f, nwf, cnt, cursor,
                                                 sums, cnts_g, N, G);
    }

    // ---- CSR build (dst-sorted edges) ----
    hist_kernel<<<(E + 255) / 256, 256, 0, stream>>>(dstI, cnt, E);
    scan_kernel<<<1, 1024, 0, stream>>>(cnt, rowptr, N);
    scatter_kernel<<<(E + 255) / 256, 256, 0, stream>>>(
        srcI, dstI, edge_attr, rowptr, cursor, srcS, dstS, eaS, E);

    // embed + zero agg + counts + layer-0 projections (one kernel)
    embed_ys_kernel<<<(N + 31) / 32, 256, 0, stream>>>(
        z, emb, xb, agg, batch, cnts_g, w1sf, w1bf, Ys, Y, N);

    for (int l = 0; l < 4; ++l) {
        edge_mfma<<<(E + 63) / 64, 512, 0, stream>>>(
            srcS, dstS, eaS,
            w1tf + (size_t)l * 8 * 512, eb1 + (size_t)l * HID,
            w2f + (size_t)l * 32 * 512, eb2 + (size_t)l * HID,
            Ys, Y, agg, E);
        int lnxt = (l + 1) & 3;   // l==3: tail skipped (last=1), args unused
        node_mfma<<<(N + 31) / 32, 256, 0, stream>>>(
            xb, agg, nwf + (size_t)l * 64 * 512, nb + (size_t)l * HID,
            batch, sums,
            w1sf + (size_t)lnxt * 32 * 512, w1bf + (size_t)lnxt * 32 * 512,
            Ys, Y, (l == 3) ? 1 : 0, N);
    }

    readout_kernel<<<G, HID, 0, stream>>>(sums, cnts_g, rw1, rb1, rw2, rb2, pred);
}